// Round 1
// baseline (446.541 us; speedup 1.0000x reference)
//
#include <hip/hip_runtime.h>
#include <math.h>

// ---------------------------------------------------------------------------
// Refine_Attn: 3-level neighborhood-attention pyramid, fp32.
// Stage 1: C=32,  H=24, W=48
// Stage 2: C=64,  H=48, W=96
// Stage 3: C=128, H=96, W=192
// k=5 neighborhood, rpb bias (9x9), softmax over 25, proj, bilinear up2x.
// ---------------------------------------------------------------------------

// Transpose (C,H*W) -> (H*W,C)
__global__ void chw_to_hwc(const float* __restrict__ in, float* __restrict__ out,
                           int C, int HW) {
    int idx = blockIdx.x * blockDim.x + threadIdx.x;
    if (idx >= C * HW) return;
    int hw = idx / C;
    int c  = idx - hw * C;
    out[idx] = in[c * HW + hw];
}

// out[m][n] = sum_k A[m][k] * Wt[k][n] + bias[n]; first `qcols` columns scaled
// by qscale AFTER bias (matches reference: q = (x@w+b)[:,:C] * scale).
// MT rows per block, blockDim = N threads. transpose_out: out[n][m] (CHW).
template <int MT>
__global__ void mm_bias(const float* __restrict__ A, const float* __restrict__ Wt,
                        const float* __restrict__ bias, float* __restrict__ out,
                        int M, int K, int N, int qcols, float qscale,
                        int transpose_out) {
    extern __shared__ float As[];  // MT*K floats
    const int m0 = blockIdx.x * MT;
    const int n  = threadIdx.x;
    for (int idx = n; idx < MT * K; idx += blockDim.x)
        As[idx] = A[(size_t)m0 * K + idx];  // MT contiguous rows
    __syncthreads();

    float acc[MT];
#pragma unroll
    for (int r = 0; r < MT; ++r) acc[r] = bias[n];
    for (int k = 0; k < K; ++k) {
        float wv = Wt[(size_t)k * N + n];
#pragma unroll
        for (int r = 0; r < MT; ++r) acc[r] = fmaf(As[r * K + k], wv, acc[r]);
    }
    if (n < qcols) {
#pragma unroll
        for (int r = 0; r < MT; ++r) acc[r] *= qscale;
    }
    if (transpose_out) {
        // 16 consecutive floats along m per thread -> 4x float4 stores
        float4* o = (float4*)(out + (size_t)n * M + m0);
#pragma unroll
        for (int r4 = 0; r4 < MT / 4; ++r4)
            o[r4] = make_float4(acc[4 * r4], acc[4 * r4 + 1],
                                acc[4 * r4 + 2], acc[4 * r4 + 3]);
    } else {
#pragma unroll
        for (int r = 0; r < MT; ++r) out[(size_t)(m0 + r) * N + n] = acc[r];
    }
}

// Neighborhood attention (pre-proj). qkv layout (H*W, 3C): q|k|v.
// One wave (64 threads) per pixel. Lanes 0..24 each own one neighbor.
__global__ void na2d_attn(const float* __restrict__ qkv,
                          const float* __restrict__ rpb,
                          float* __restrict__ out, int H, int W, int C) {
    const int pix  = blockIdx.x;
    const int h    = pix / W;
    const int w    = pix - h * W;
    const int lane = threadIdx.x;

    const int h0 = min(max(h - 2, 0), H - 5);
    const int w0 = min(max(w - 2, 0), W - 5);

    __shared__ float a_s[25];

    float logit = -INFINITY;
    if (lane < 25) {
        const int i  = lane / 5;
        const int j  = lane - i * 5;
        const int nh = h0 + i;
        const int nw = w0 + j;
        const float* qp = qkv + (size_t)pix * 3 * C;                  // q
        const float* kp = qkv + ((size_t)(nh * W + nw) * 3 * C + C);  // k
        float s = 0.f;
        for (int c = 0; c < C; ++c) s = fmaf(qp[c], kp[c], s);
        const int bi = nh - h + 4;
        const int bj = nw - w + 4;
        logit = s + rpb[bi * 9 + bj];
    }
    // wave-wide max / sum (inactive lanes contribute -inf / 0)
    float mx = logit;
    for (int off = 32; off; off >>= 1) mx = fmaxf(mx, __shfl_xor(mx, off));
    float p = (lane < 25) ? expf(logit - mx) : 0.f;
    float sum = p;
    for (int off = 32; off; off >>= 1) sum += __shfl_xor(sum, off);
    if (lane < 25) a_s[lane] = p / sum;
    __syncthreads();

    // PV: each lane handles channels lane, lane+64, ...
    for (int c = lane; c < C; c += 64) {
        float acc = 0.f;
#pragma unroll
        for (int j = 0; j < 25; ++j) {
            const int nh = h0 + j / 5;
            const int nw = w0 + (j - (j / 5) * 5);
            acc = fmaf(a_s[j], qkv[(size_t)(nh * W + nw) * 3 * C + 2 * C + c], acc);
        }
        out[(size_t)pix * C + c] = acc;
    }
}

// Fused bilinear up2x (align_corners-style, matching reference weights) + matmul.
// y: (Hs,Ws,Cin). out: (2Hs,2Ws,Cout) = up2x(y) @ Wm + bm. blockDim = Cout.
__global__ void up2x_mm(const float* __restrict__ y, const float* __restrict__ Wm,
                        const float* __restrict__ bm, float* __restrict__ out,
                        int Hs, int Ws, int Cin, int Cout) {
    extern __shared__ float xs[];  // Cin floats
    const int Hd = 2 * Hs, Wd = 2 * Ws;
    const int pix = blockIdx.x;
    const int h2  = pix / Wd;
    const int w2  = pix - h2 * Wd;
    const int n   = threadIdx.x;

    const float ph = (float)h2 * (float)(Hs - 1) / (float)(Hd - 1);
    int h0i = (int)floorf(ph);
    int h1i = min(h0i + 1, Hs - 1);
    const float wh = ph - (float)h0i;
    const float pw = (float)w2 * (float)(Ws - 1) / (float)(Wd - 1);
    int w0i = (int)floorf(pw);
    int w1i = min(w0i + 1, Ws - 1);
    const float ww = pw - (float)w0i;

    for (int c = n; c < Cin; c += blockDim.x) {
        float v00 = y[((size_t)h0i * Ws + w0i) * Cin + c];
        float v01 = y[((size_t)h0i * Ws + w1i) * Cin + c];
        float v10 = y[((size_t)h1i * Ws + w0i) * Cin + c];
        float v11 = y[((size_t)h1i * Ws + w1i) * Cin + c];
        float t0 = v00 * (1.f - wh) + v10 * wh;   // H-axis first (as reference)
        float t1 = v01 * (1.f - wh) + v11 * wh;
        xs[c] = t0 * (1.f - ww) + t1 * ww;
    }
    __syncthreads();

    float acc = bm[n];
    for (int k = 0; k < Cin; ++k) acc = fmaf(xs[k], Wm[(size_t)k * Cout + n], acc);
    out[(size_t)pix * Cout + n] = acc;
}

extern "C" void kernel_launch(void* const* d_in, const int* in_sizes, int n_in,
                              void* d_out, int out_size, void* d_ws, size_t ws_size,
                              hipStream_t stream) {
    const float* attn    = (const float*)d_in[0];
    const float* w_qkv1  = (const float*)d_in[1];
    const float* b_qkv1  = (const float*)d_in[2];
    const float* w_proj1 = (const float*)d_in[3];
    const float* b_proj1 = (const float*)d_in[4];
    const float* rpb1    = (const float*)d_in[5];
    const float* w_qkv2  = (const float*)d_in[6];
    const float* b_qkv2  = (const float*)d_in[7];
    const float* w_proj2 = (const float*)d_in[8];
    const float* b_proj2 = (const float*)d_in[9];
    const float* rpb2    = (const float*)d_in[10];
    const float* w_qkv3  = (const float*)d_in[11];
    const float* b_qkv3  = (const float*)d_in[12];
    const float* w_proj3 = (const float*)d_in[13];
    const float* b_proj3 = (const float*)d_in[14];
    const float* rpb3    = (const float*)d_in[15];
    const float* w_up1   = (const float*)d_in[16];
    const float* b_up1   = (const float*)d_in[17];
    const float* w_up2   = (const float*)d_in[18];
    const float* b_up2   = (const float*)d_in[19];
    float* out = (float*)d_out;

    float* ws   = (float*)d_ws;
    float* bufA = ws;                        // x inputs  (max 18432*128 = 2,359,296)
    float* bufB = bufA + 2359296;            // qkv       (max 18432*384 = 7,077,888)
    float* bufC = bufB + 7077888;            // attn out  (max 2,359,296)
    float* bufD = bufC + 2359296;            // y         (max 4608*64  =   294,912)
    // peak ws use: ~48.4 MB

    // ---- Stage 1: C=32, 24x48 ----
    {
        const int H = 24, W = 48, C = 32, M = H * W;
        chw_to_hwc<<<(C * M + 255) / 256, 256, 0, stream>>>(attn, bufA, C, M);
        mm_bias<16><<<M / 16, 3 * C, 16 * C * 4, stream>>>(
            bufA, w_qkv1, b_qkv1, bufB, M, C, 3 * C, C, 1.f / sqrtf((float)C), 0);
        na2d_attn<<<M, 64, 0, stream>>>(bufB, rpb1, bufC, H, W, C);
        mm_bias<16><<<M / 16, C, 16 * C * 4, stream>>>(
            bufC, w_proj1, b_proj1, bufD, M, C, C, 0, 1.f, 0);
        up2x_mm<<<4 * M, 64, C * 4, stream>>>(bufD, w_up1, b_up1, bufA, H, W, C, 64);
    }
    // ---- Stage 2: C=64, 48x96 ----
    {
        const int H = 48, W = 96, C = 64, M = H * W;
        mm_bias<16><<<M / 16, 3 * C, 16 * C * 4, stream>>>(
            bufA, w_qkv2, b_qkv2, bufB, M, C, 3 * C, C, 1.f / sqrtf((float)C), 0);
        na2d_attn<<<M, 64, 0, stream>>>(bufB, rpb2, bufC, H, W, C);
        mm_bias<16><<<M / 16, C, 16 * C * 4, stream>>>(
            bufC, w_proj2, b_proj2, bufD, M, C, C, 0, 1.f, 0);
        up2x_mm<<<4 * M, 128, C * 4, stream>>>(bufD, w_up2, b_up2, bufA, H, W, C, 128);
    }
    // ---- Stage 3: C=128, 96x192 ----
    {
        const int H = 96, W = 192, C = 128, M = H * W;
        mm_bias<16><<<M / 16, 3 * C, 16 * C * 4, stream>>>(
            bufA, w_qkv3, b_qkv3, bufB, M, C, 3 * C, C, 1.f / sqrtf((float)C), 0);
        na2d_attn<<<M, 64, 0, stream>>>(bufB, rpb3, bufC, H, W, C);
        mm_bias<16><<<M / 16, C, 16 * C * 4, stream>>>(
            bufC, w_proj3, b_proj3, out, M, C, C, 0, 1.f, 1);  // transposed -> CHW
    }
}

// Round 2
// 297.213 us; speedup vs baseline: 1.5024x; 1.5024x over previous
//
#include <hip/hip_runtime.h>
#include <math.h>

// ---------------------------------------------------------------------------
// Refine_Attn: 3-level neighborhood-attention pyramid, fp32.
// Stage 1: C=32,  H=24, W=48
// Stage 2: C=64,  H=48, W=96
// Stage 3: C=128, H=96, W=192
// k=5 neighborhood, rpb bias (9x9), softmax over 25, proj, bilinear up2x.
// ---------------------------------------------------------------------------

// Transpose (C,H*W) -> (H*W,C)
__global__ void chw_to_hwc(const float* __restrict__ in, float* __restrict__ out,
                           int C, int HW) {
    int idx = blockIdx.x * blockDim.x + threadIdx.x;
    if (idx >= C * HW) return;
    int hw = idx / C;
    int c  = idx - hw * C;
    out[idx] = in[c * HW + hw];
}

// out[m][n] = sum_k A[m][k] * Wt[k][n] + bias[n]; first `qcols` columns scaled
// by qscale AFTER bias. MT rows per block, blockDim = N threads.
// transpose_out: out[n][m] (CHW).
template <int MT>
__global__ void mm_bias(const float* __restrict__ A, const float* __restrict__ Wt,
                        const float* __restrict__ bias, float* __restrict__ out,
                        int M, int K, int N, int qcols, float qscale,
                        int transpose_out) {
    extern __shared__ float As[];  // MT*K floats
    const int m0 = blockIdx.x * MT;
    const int n  = threadIdx.x;
    for (int idx = n; idx < MT * K; idx += blockDim.x)
        As[idx] = A[(size_t)m0 * K + idx];
    __syncthreads();

    float acc[MT];
#pragma unroll
    for (int r = 0; r < MT; ++r) acc[r] = bias[n];
    for (int k = 0; k < K; ++k) {
        float wv = Wt[(size_t)k * N + n];
#pragma unroll
        for (int r = 0; r < MT; ++r) acc[r] = fmaf(As[r * K + k], wv, acc[r]);
    }
    if (n < qcols) {
#pragma unroll
        for (int r = 0; r < MT; ++r) acc[r] *= qscale;
    }
    if (transpose_out) {
        float4* o = (float4*)(out + (size_t)n * M + m0);
#pragma unroll
        for (int r4 = 0; r4 < MT / 4; ++r4)
            o[r4] = make_float4(acc[4 * r4], acc[4 * r4 + 1],
                                acc[4 * r4 + 2], acc[4 * r4 + 3]);
    } else {
#pragma unroll
        for (int r = 0; r < MT; ++r) out[(size_t)(m0 + r) * N + n] = acc[r];
    }
}

// Neighborhood attention, channel-parallel. qkv layout (H*W, 3C): q|k|v.
// One wave per pixel, 4 pixels per 256-thread block.
// Lane l owns channels [l*VPL, l*VPL+VPL). Every K/V read is a coalesced
// wave-wide load with wave-uniform base; 25 independent loads issue together.
// QK partial dots reduced with a 6-step shfl_xor butterfly.
template <int C>
__global__ __launch_bounds__(256) void na2d_attn_v2(
        const float* __restrict__ qkv, const float* __restrict__ rpb,
        float* __restrict__ out, int H, int W) {
    constexpr int VPL = (C + 63) / 64;   // floats per lane: 1 (C<=64) or 2 (C=128)
    const int lane = threadIdx.x & 63;
    const int wid  = threadIdx.x >> 6;
    const int pix  = (blockIdx.x << 2) + wid;
    const int h = pix / W;
    const int w = pix - h * W;
    const int h0 = min(max(h - 2, 0), H - 5);
    const int w0 = min(max(w - 2, 0), W - 5);
    const int cb = lane * VPL;
    const bool act = (C >= 64) || (cb < C);

    // q fragment
    float q0 = 0.f, q1 = 0.f;
    {
        const float* qp = qkv + (size_t)pix * (3 * C) + cb;
        if constexpr (VPL == 2) {
            float2 t = *(const float2*)qp;
            q0 = t.x; q1 = t.y;
        } else {
            if (act) q0 = qp[0];
        }
    }

    // QK^T partials: 25 coalesced loads, all independent
    float p[25];
#pragma unroll
    for (int j = 0; j < 25; ++j) {
        const int nh = h0 + j / 5;
        const int nw = w0 + j % 5;
        const float* kp = qkv + (size_t)(nh * W + nw) * (3 * C) + C + cb;
        float s = 0.f;
        if constexpr (VPL == 2) {
            float2 t = *(const float2*)kp;
            s = fmaf(q0, t.x, q1 * t.y);
        } else {
            if (act) s = q0 * kp[0];
        }
        p[j] = s;
    }

    // butterfly-reduce each logit across the wave, then add rpb bias
#pragma unroll
    for (int j = 0; j < 25; ++j) {
        float v = p[j];
        v += __shfl_xor(v, 1);
        v += __shfl_xor(v, 2);
        v += __shfl_xor(v, 4);
        v += __shfl_xor(v, 8);
        v += __shfl_xor(v, 16);
        v += __shfl_xor(v, 32);
        const int nh = h0 + j / 5;
        const int nw = w0 + j % 5;
        p[j] = v + rpb[(nh - h + 4) * 9 + (nw - w + 4)];
    }

    // softmax over 25 (redundant per-lane, registers only)
    float mx = p[0];
#pragma unroll
    for (int j = 1; j < 25; ++j) mx = fmaxf(mx, p[j]);
    float sum = 0.f;
#pragma unroll
    for (int j = 0; j < 25; ++j) {
        p[j] = expf(p[j] - mx);
        sum += p[j];
    }
    const float inv = 1.f / sum;

    // PV: 25 coalesced loads
    float a0 = 0.f, a1 = 0.f;
#pragma unroll
    for (int j = 0; j < 25; ++j) {
        const int nh = h0 + j / 5;
        const int nw = w0 + j % 5;
        const float* vp = qkv + (size_t)(nh * W + nw) * (3 * C) + 2 * C + cb;
        if constexpr (VPL == 2) {
            float2 t = *(const float2*)vp;
            a0 = fmaf(p[j], t.x, a0);
            a1 = fmaf(p[j], t.y, a1);
        } else {
            if (act) a0 = fmaf(p[j], vp[0], a0);
        }
    }
    if constexpr (VPL == 2) {
        *(float2*)(out + (size_t)pix * C + cb) = make_float2(a0 * inv, a1 * inv);
    } else {
        if (act) out[(size_t)pix * C + cb] = a0 * inv;
    }
}

// Fused bilinear up2x + matmul. y: (Hs,Ws,Cin). out: (2Hs,2Ws,Cout).
__global__ void up2x_mm(const float* __restrict__ y, const float* __restrict__ Wm,
                        const float* __restrict__ bm, float* __restrict__ out,
                        int Hs, int Ws, int Cin, int Cout) {
    extern __shared__ float xs[];  // Cin floats
    const int Hd = 2 * Hs, Wd = 2 * Ws;
    const int pix = blockIdx.x;
    const int h2  = pix / Wd;
    const int w2  = pix - h2 * Wd;
    const int n   = threadIdx.x;

    const float ph = (float)h2 * (float)(Hs - 1) / (float)(Hd - 1);
    int h0i = (int)floorf(ph);
    int h1i = min(h0i + 1, Hs - 1);
    const float wh = ph - (float)h0i;
    const float pw = (float)w2 * (float)(Ws - 1) / (float)(Wd - 1);
    int w0i = (int)floorf(pw);
    int w1i = min(w0i + 1, Ws - 1);
    const float ww = pw - (float)w0i;

    for (int c = n; c < Cin; c += blockDim.x) {
        float v00 = y[((size_t)h0i * Ws + w0i) * Cin + c];
        float v01 = y[((size_t)h0i * Ws + w1i) * Cin + c];
        float v10 = y[((size_t)h1i * Ws + w0i) * Cin + c];
        float v11 = y[((size_t)h1i * Ws + w1i) * Cin + c];
        float t0 = v00 * (1.f - wh) + v10 * wh;
        float t1 = v01 * (1.f - wh) + v11 * wh;
        xs[c] = t0 * (1.f - ww) + t1 * ww;
    }
    __syncthreads();

    float acc = bm[n];
    for (int k = 0; k < Cin; ++k) acc = fmaf(xs[k], Wm[(size_t)k * Cout + n], acc);
    out[(size_t)pix * Cout + n] = acc;
}

extern "C" void kernel_launch(void* const* d_in, const int* in_sizes, int n_in,
                              void* d_out, int out_size, void* d_ws, size_t ws_size,
                              hipStream_t stream) {
    const float* attn    = (const float*)d_in[0];
    const float* w_qkv1  = (const float*)d_in[1];
    const float* b_qkv1  = (const float*)d_in[2];
    const float* w_proj1 = (const float*)d_in[3];
    const float* b_proj1 = (const float*)d_in[4];
    const float* rpb1    = (const float*)d_in[5];
    const float* w_qkv2  = (const float*)d_in[6];
    const float* b_qkv2  = (const float*)d_in[7];
    const float* w_proj2 = (const float*)d_in[8];
    const float* b_proj2 = (const float*)d_in[9];
    const float* rpb2    = (const float*)d_in[10];
    const float* w_qkv3  = (const float*)d_in[11];
    const float* b_qkv3  = (const float*)d_in[12];
    const float* w_proj3 = (const float*)d_in[13];
    const float* b_proj3 = (const float*)d_in[14];
    const float* rpb3    = (const float*)d_in[15];
    const float* w_up1   = (const float*)d_in[16];
    const float* b_up1   = (const float*)d_in[17];
    const float* w_up2   = (const float*)d_in[18];
    const float* b_up2   = (const float*)d_in[19];
    float* out = (float*)d_out;

    float* ws   = (float*)d_ws;
    float* bufA = ws;                        // x inputs  (max 18432*128)
    float* bufB = bufA + 2359296;            // qkv       (max 18432*384)
    float* bufC = bufB + 7077888;            // attn out  (max 18432*128)
    float* bufD = bufC + 2359296;            // y         (max 4608*64)

    // ---- Stage 1: C=32, 24x48 ----
    {
        const int H = 24, W = 48, C = 32, M = H * W;
        chw_to_hwc<<<(C * M + 255) / 256, 256, 0, stream>>>(attn, bufA, C, M);
        mm_bias<16><<<M / 16, 3 * C, 16 * C * 4, stream>>>(
            bufA, w_qkv1, b_qkv1, bufB, M, C, 3 * C, C, 1.f / sqrtf((float)C), 0);
        na2d_attn_v2<32><<<M / 4, 256, 0, stream>>>(bufB, rpb1, bufC, H, W);
        mm_bias<16><<<M / 16, C, 16 * C * 4, stream>>>(
            bufC, w_proj1, b_proj1, bufD, M, C, C, 0, 1.f, 0);
        up2x_mm<<<4 * M, 64, C * 4, stream>>>(bufD, w_up1, b_up1, bufA, H, W, C, 64);
    }
    // ---- Stage 2: C=64, 48x96 ----
    {
        const int H = 48, W = 96, C = 64, M = H * W;
        mm_bias<16><<<M / 16, 3 * C, 16 * C * 4, stream>>>(
            bufA, w_qkv2, b_qkv2, bufB, M, C, 3 * C, C, 1.f / sqrtf((float)C), 0);
        na2d_attn_v2<64><<<M / 4, 256, 0, stream>>>(bufB, rpb2, bufC, H, W);
        mm_bias<16><<<M / 16, C, 16 * C * 4, stream>>>(
            bufC, w_proj2, b_proj2, bufD, M, C, C, 0, 1.f, 0);
        up2x_mm<<<4 * M, 128, C * 4, stream>>>(bufD, w_up2, b_up2, bufA, H, W, C, 128);
    }
    // ---- Stage 3: C=128, 96x192 ----
    {
        const int H = 96, W = 192, C = 128, M = H * W;
        mm_bias<16><<<M / 16, 3 * C, 16 * C * 4, stream>>>(
            bufA, w_qkv3, b_qkv3, bufB, M, C, 3 * C, C, 1.f / sqrtf((float)C), 0);
        na2d_attn_v2<128><<<M / 4, 256, 0, stream>>>(bufB, rpb3, bufC, H, W);
        mm_bias<16><<<M / 16, C, 16 * C * 4, stream>>>(
            bufC, w_proj3, b_proj3, out, M, C, C, 0, 1.f, 1);  // -> CHW
    }
}

// Round 3
// 263.127 us; speedup vs baseline: 1.6971x; 1.1295x over previous
//
#include <hip/hip_runtime.h>
#include <math.h>

// ---------------------------------------------------------------------------
// Refine_Attn: 3-level neighborhood-attention pyramid, fp32.
// Stage 1: C=32,  H=24, W=48 | Stage 2: C=64, H=48, W=96 | Stage 3: C=128, 96x192
// k=5 neighborhood, rpb bias (9x9), softmax over 25, proj, bilinear up2x.
// ---------------------------------------------------------------------------

// Transpose (C,H*W) -> (H*W,C)
__global__ void chw_to_hwc(const float* __restrict__ in, float* __restrict__ out,
                           int C, int HW) {
    int idx = blockIdx.x * blockDim.x + threadIdx.x;
    if (idx >= C * HW) return;
    int hw = idx / C;
    int c  = idx - hw * C;
    out[idx] = in[c * HW + hw];
}

// out[m][n] = sum_k A[m][k]*Wt[k][n] + bias[n]; first qcols columns scaled by
// qscale. MT rows/block, blockDim=N. k unrolled x4 with float4 LDS reads.
template <int MT>
__global__ void mm_bias(const float* __restrict__ A, const float* __restrict__ Wt,
                        const float* __restrict__ bias, float* __restrict__ out,
                        int M, int K, int N, int qcols, float qscale,
                        int transpose_out) {
    extern __shared__ float As[];  // MT*K floats
    const int m0 = blockIdx.x * MT;
    const int n  = threadIdx.x;
    {   // vectorized staging: MT contiguous rows
        const float4* src = (const float4*)(A + (size_t)m0 * K);
        float4* dst = (float4*)As;
        for (int idx = n; idx < MT * K / 4; idx += blockDim.x) dst[idx] = src[idx];
    }
    __syncthreads();

    float acc[MT];
#pragma unroll
    for (int r = 0; r < MT; ++r) acc[r] = bias[n];
    for (int k = 0; k < K; k += 4) {
        const float* wp = Wt + (size_t)k * N + n;
        const float w0 = wp[0];
        const float w1 = wp[N];
        const float w2 = wp[2 * N];
        const float w3 = wp[3 * N];
#pragma unroll
        for (int r = 0; r < MT; ++r) {
            float4 a4 = *(const float4*)&As[r * K + k];
            acc[r] = fmaf(a4.x, w0, acc[r]);
            acc[r] = fmaf(a4.y, w1, acc[r]);
            acc[r] = fmaf(a4.z, w2, acc[r]);
            acc[r] = fmaf(a4.w, w3, acc[r]);
        }
    }
    if (n < qcols) {
#pragma unroll
        for (int r = 0; r < MT; ++r) acc[r] *= qscale;
    }
    if (transpose_out) {
        float4* o = (float4*)(out + (size_t)n * M + m0);
#pragma unroll
        for (int r4 = 0; r4 < MT / 4; ++r4)
            o[r4] = make_float4(acc[4 * r4], acc[4 * r4 + 1],
                                acc[4 * r4 + 2], acc[4 * r4 + 3]);
    } else {
#pragma unroll
        for (int r = 0; r < MT; ++r) out[(size_t)(m0 + r) * N + n] = acc[r];
    }
}

template <int VPL>
__device__ inline void loadv(const float* __restrict__ p, float* d) {
    if constexpr (VPL == 2) {
        float2 t = *(const float2*)p;
        d[0] = t.x; d[1] = t.y;
    } else if constexpr (VPL == 4) {
        float4 t = *(const float4*)p;
        d[0] = t.x; d[1] = t.y; d[2] = t.z; d[3] = t.w;
    } else {
        float4 t0 = *(const float4*)p;
        float4 t1 = *(const float4*)(p + 4);
        d[0] = t0.x; d[1] = t0.y; d[2] = t0.z; d[3] = t0.w;
        d[4] = t1.x; d[5] = t1.y; d[6] = t1.z; d[7] = t1.w;
    }
}

// Neighborhood attention, 4 pixels per wave (16-lane channel groups).
// qkv layout (H*W, 3C): q|k|v. Lane group g owns pixel quad*4+g; lane li
// within the group owns channels [li*VPL, li*VPL+VPL). All K/V reads are
// wave-coalesced; QK reduced with a 4-step shfl_xor butterfly within 16 lanes.
template <int C>
__global__ __launch_bounds__(256) void na2d_attn_v3(
        const float* __restrict__ qkv, const float* __restrict__ rpb,
        float* __restrict__ out, int H, int W) {
    constexpr int VPL = C / 16;  // 2 / 4 / 8
    const int lane = threadIdx.x & 63;
    const int g    = lane >> 4;
    const int li   = lane & 15;
    const int wave = threadIdx.x >> 6;
    const int pix  = (blockIdx.x * 4 + wave) * 4 + g;  // W % 4 == 0: same row per quad-group
    const int h = pix / W;
    const int w = pix - h * W;
    const int h0 = min(max(h - 2, 0), H - 5);
    const int w0 = min(max(w - 2, 0), W - 5);
    const int cb = li * VPL;

    float qf[VPL];
    loadv<VPL>(qkv + (size_t)pix * (3 * C) + cb, qf);

    // QK^T partials
    float p[25];
#pragma unroll
    for (int j = 0; j < 25; ++j) {
        const int nh = h0 + j / 5;
        const int nw = w0 + j % 5;
        float kf[VPL];
        loadv<VPL>(qkv + (size_t)(nh * W + nw) * (3 * C) + C + cb, kf);
        float s = qf[0] * kf[0];
#pragma unroll
        for (int v = 1; v < VPL; ++v) s = fmaf(qf[v], kf[v], s);
        p[j] = s;
    }
    // 16-lane butterfly + rpb
#pragma unroll
    for (int j = 0; j < 25; ++j) {
        float v = p[j];
        v += __shfl_xor(v, 1);
        v += __shfl_xor(v, 2);
        v += __shfl_xor(v, 4);
        v += __shfl_xor(v, 8);
        const int nh = h0 + j / 5;
        const int nw = w0 + j % 5;
        p[j] = v + rpb[(nh - h + 4) * 9 + (nw - w + 4)];
    }
    // softmax over 25 (registers, redundant per lane)
    float mx = p[0];
#pragma unroll
    for (int j = 1; j < 25; ++j) mx = fmaxf(mx, p[j]);
    float sum = 0.f;
#pragma unroll
    for (int j = 0; j < 25; ++j) {
        p[j] = expf(p[j] - mx);
        sum += p[j];
    }
    const float inv = 1.f / sum;

    // PV
    float a[VPL];
#pragma unroll
    for (int v = 0; v < VPL; ++v) a[v] = 0.f;
#pragma unroll
    for (int j = 0; j < 25; ++j) {
        const int nh = h0 + j / 5;
        const int nw = w0 + j % 5;
        float vf[VPL];
        loadv<VPL>(qkv + (size_t)(nh * W + nw) * (3 * C) + 2 * C + cb, vf);
#pragma unroll
        for (int v = 0; v < VPL; ++v) a[v] = fmaf(p[j], vf[v], a[v]);
    }
    float* op = out + (size_t)pix * C + cb;
    if constexpr (VPL == 2) {
        *(float2*)op = make_float2(a[0] * inv, a[1] * inv);
    } else if constexpr (VPL == 4) {
        *(float4*)op = make_float4(a[0] * inv, a[1] * inv, a[2] * inv, a[3] * inv);
    } else {
        *(float4*)op       = make_float4(a[0] * inv, a[1] * inv, a[2] * inv, a[3] * inv);
        *(float4*)(op + 4) = make_float4(a[4] * inv, a[5] * inv, a[6] * inv, a[7] * inv);
    }
}

// Fused bilinear up2x + matmul, 2x2 output quad per block (4x W_up reuse).
// y: (Hs,Ws,Cin). out: (2Hs,2Ws,Cout) = up2x(y) @ Wm + bm. blockDim = Cout.
__global__ void up2x_mm4(const float* __restrict__ y, const float* __restrict__ Wm,
                         const float* __restrict__ bm, float* __restrict__ out,
                         int Hs, int Ws, int Cin, int Cout) {
    extern __shared__ float xs[];  // 4*Cin floats
    const int Hd = 2 * Hs, Wd = 2 * Ws;
    const int a = blockIdx.x / Ws;
    const int b = blockIdx.x - a * Ws;
    const int n = threadIdx.x;

#pragma unroll
    for (int pq = 0; pq < 4; ++pq) {
        const int h2 = 2 * a + (pq >> 1);
        const int w2 = 2 * b + (pq & 1);
        const float ph = (float)h2 * (float)(Hs - 1) / (float)(Hd - 1);
        const int h0i = (int)floorf(ph);
        const int h1i = min(h0i + 1, Hs - 1);
        const float wh = ph - (float)h0i;
        const float pw = (float)w2 * (float)(Ws - 1) / (float)(Wd - 1);
        const int w0i = (int)floorf(pw);
        const int w1i = min(w0i + 1, Ws - 1);
        const float ww = pw - (float)w0i;
        for (int c = n; c < Cin; c += blockDim.x) {
            float v00 = y[((size_t)h0i * Ws + w0i) * Cin + c];
            float v01 = y[((size_t)h0i * Ws + w1i) * Cin + c];
            float v10 = y[((size_t)h1i * Ws + w0i) * Cin + c];
            float v11 = y[((size_t)h1i * Ws + w1i) * Cin + c];
            float t0 = v00 * (1.f - wh) + v10 * wh;
            float t1 = v01 * (1.f - wh) + v11 * wh;
            xs[pq * Cin + c] = t0 * (1.f - ww) + t1 * ww;
        }
    }
    __syncthreads();

    float acc0 = bm[n], acc1 = acc0, acc2 = acc0, acc3 = acc0;
    for (int k = 0; k < Cin; k += 4) {
        const float* wp = Wm + (size_t)k * Cout + n;
        const float w0c = wp[0];
        const float w1c = wp[Cout];
        const float w2c = wp[2 * Cout];
        const float w3c = wp[3 * Cout];
        float4 x0 = *(const float4*)&xs[0 * Cin + k];
        float4 x1 = *(const float4*)&xs[1 * Cin + k];
        float4 x2 = *(const float4*)&xs[2 * Cin + k];
        float4 x3 = *(const float4*)&xs[3 * Cin + k];
        acc0 = fmaf(x0.x, w0c, acc0); acc0 = fmaf(x0.y, w1c, acc0);
        acc0 = fmaf(x0.z, w2c, acc0); acc0 = fmaf(x0.w, w3c, acc0);
        acc1 = fmaf(x1.x, w0c, acc1); acc1 = fmaf(x1.y, w1c, acc1);
        acc1 = fmaf(x1.z, w2c, acc1); acc1 = fmaf(x1.w, w3c, acc1);
        acc2 = fmaf(x2.x, w0c, acc2); acc2 = fmaf(x2.y, w1c, acc2);
        acc2 = fmaf(x2.z, w2c, acc2); acc2 = fmaf(x2.w, w3c, acc2);
        acc3 = fmaf(x3.x, w0c, acc3); acc3 = fmaf(x3.y, w1c, acc3);
        acc3 = fmaf(x3.z, w2c, acc3); acc3 = fmaf(x3.w, w3c, acc3);
    }
    const size_t base = ((size_t)(2 * a) * Wd + 2 * b) * Cout + n;
    out[base]              = acc0;
    out[base + Cout]       = acc1;
    out[base + (size_t)Wd * Cout]        = acc2;
    out[base + (size_t)Wd * Cout + Cout] = acc3;
}

extern "C" void kernel_launch(void* const* d_in, const int* in_sizes, int n_in,
                              void* d_out, int out_size, void* d_ws, size_t ws_size,
                              hipStream_t stream) {
    const float* attn    = (const float*)d_in[0];
    const float* w_qkv1  = (const float*)d_in[1];
    const float* b_qkv1  = (const float*)d_in[2];
    const float* w_proj1 = (const float*)d_in[3];
    const float* b_proj1 = (const float*)d_in[4];
    const float* rpb1    = (const float*)d_in[5];
    const float* w_qkv2  = (const float*)d_in[6];
    const float* b_qkv2  = (const float*)d_in[7];
    const float* w_proj2 = (const float*)d_in[8];
    const float* b_proj2 = (const float*)d_in[9];
    const float* rpb2    = (const float*)d_in[10];
    const float* w_qkv3  = (const float*)d_in[11];
    const float* b_qkv3  = (const float*)d_in[12];
    const float* w_proj3 = (const float*)d_in[13];
    const float* b_proj3 = (const float*)d_in[14];
    const float* rpb3    = (const float*)d_in[15];
    const float* w_up1   = (const float*)d_in[16];
    const float* b_up1   = (const float*)d_in[17];
    const float* w_up2   = (const float*)d_in[18];
    const float* b_up2   = (const float*)d_in[19];
    float* out = (float*)d_out;

    float* ws   = (float*)d_ws;
    float* bufA = ws;                        // x inputs  (max 18432*128)
    float* bufB = bufA + 2359296;            // qkv       (max 18432*384)
    float* bufC = bufB + 7077888;            // attn out  (max 18432*128)
    float* bufD = bufC + 2359296;            // y         (max 4608*64)

    // ---- Stage 1: C=32, 24x48 ----
    {
        const int H = 24, W = 48, C = 32, M = H * W;
        chw_to_hwc<<<(C * M + 255) / 256, 256, 0, stream>>>(attn, bufA, C, M);
        mm_bias<16><<<M / 16, 3 * C, 16 * C * 4, stream>>>(
            bufA, w_qkv1, b_qkv1, bufB, M, C, 3 * C, C, 1.f / sqrtf((float)C), 0);
        na2d_attn_v3<32><<<M / 16, 256, 0, stream>>>(bufB, rpb1, bufC, H, W);
        mm_bias<16><<<M / 16, C, 16 * C * 4, stream>>>(
            bufC, w_proj1, b_proj1, bufD, M, C, C, 0, 1.f, 0);
        up2x_mm4<<<H * W, 64, 4 * C * 4, stream>>>(bufD, w_up1, b_up1, bufA, H, W, C, 64);
    }
    // ---- Stage 2: C=64, 48x96 ----
    {
        const int H = 48, W = 96, C = 64, M = H * W;
        mm_bias<16><<<M / 16, 3 * C, 16 * C * 4, stream>>>(
            bufA, w_qkv2, b_qkv2, bufB, M, C, 3 * C, C, 1.f / sqrtf((float)C), 0);
        na2d_attn_v3<64><<<M / 16, 256, 0, stream>>>(bufB, rpb2, bufC, H, W);
        mm_bias<16><<<M / 16, C, 16 * C * 4, stream>>>(
            bufC, w_proj2, b_proj2, bufD, M, C, C, 0, 1.f, 0);
        up2x_mm4<<<H * W, 128, 4 * C * 4, stream>>>(bufD, w_up2, b_up2, bufA, H, W, C, 128);
    }
    // ---- Stage 3: C=128, 96x192 ----
    {
        const int H = 96, W = 192, C = 128, M = H * W;
        mm_bias<32><<<M / 32, 3 * C, 32 * C * 4, stream>>>(
            bufA, w_qkv3, b_qkv3, bufB, M, C, 3 * C, C, 1.f / sqrtf((float)C), 0);
        na2d_attn_v3<128><<<M / 16, 256, 0, stream>>>(bufB, rpb3, bufC, H, W);
        mm_bias<32><<<M / 32, C, 32 * C * 4, stream>>>(
            bufC, w_proj3, b_proj3, out, M, C, C, 0, 1.f, 1);  // -> CHW
    }
}

// Round 5
// 182.636 us; speedup vs baseline: 2.4450x; 1.4407x over previous
//
#include <hip/hip_runtime.h>
#include <math.h>

// ---------------------------------------------------------------------------
// Refine_Attn: 3-level neighborhood-attention pyramid, fp32.
// Stage 1: C=32,  H=24, W=48 | Stage 2: C=64, H=48, W=96 | Stage 3: C=128, 96x192
// k=5 neighborhood, rpb bias (9x9), softmax over 25, proj, bilinear up2x.
// ---------------------------------------------------------------------------

// Transpose (C,H*W) -> (H*W,C)
__global__ void chw_to_hwc(const float* __restrict__ in, float* __restrict__ out,
                           int C, int HW) {
    int idx = blockIdx.x * blockDim.x + threadIdx.x;
    if (idx >= C * HW) return;
    int hw = idx / C;
    int c  = idx - hw * C;
    out[idx] = in[c * HW + hw];
}

// Small-matrix fallback (stage 1 only). out[m][n]=sum_k A[m][k]*Wt[k][n]+bias[n].
template <int MT>
__global__ void mm_bias(const float* __restrict__ A, const float* __restrict__ Wt,
                        const float* __restrict__ bias, float* __restrict__ out,
                        int M, int K, int N, int qcols, float qscale) {
    extern __shared__ float As[];  // MT*K floats
    const int m0 = blockIdx.x * MT;
    const int n  = threadIdx.x;
    {
        const float4* src = (const float4*)(A + (size_t)m0 * K);
        float4* dst = (float4*)As;
        for (int idx = n; idx < MT * K / 4; idx += blockDim.x) dst[idx] = src[idx];
    }
    __syncthreads();

    float acc[MT];
#pragma unroll
    for (int r = 0; r < MT; ++r) acc[r] = bias[n];
    for (int k = 0; k < K; k += 4) {
        const float* wp = Wt + (size_t)k * N + n;
        const float w0 = wp[0];
        const float w1 = wp[N];
        const float w2 = wp[2 * N];
        const float w3 = wp[3 * N];
#pragma unroll
        for (int r = 0; r < MT; ++r) {
            float4 a4 = *(const float4*)&As[r * K + k];
            acc[r] = fmaf(a4.x, w0, acc[r]);
            acc[r] = fmaf(a4.y, w1, acc[r]);
            acc[r] = fmaf(a4.z, w2, acc[r]);
            acc[r] = fmaf(a4.w, w3, acc[r]);
        }
    }
    if (n < qcols) {
#pragma unroll
        for (int r = 0; r < MT; ++r) acc[r] *= qscale;
    }
#pragma unroll
    for (int r = 0; r < MT; ++r) out[(size_t)(m0 + r) * N + n] = acc[r];
}

// Register-tiled GEMM: out = A(M,K) @ Wt(K,N) + bias; first qcols cols scaled
// by qscale after bias. Block tile 64 x BN, BK=16, 256 threads, thread tile
// 4 x NT (BN/NT must be 16). TRANS: out[n][m] (CHW). M%64==0, K%16==0, N%BN==0.
template <int BN, int NT, int TRANS>
__global__ __launch_bounds__(256) void gemm_rt(
        const float* __restrict__ A, const float* __restrict__ Wt,
        const float* __restrict__ bias, float* __restrict__ out,
        int M, int K, int N, int qcols, float qscale) {
    constexpr int BM = 64, BK = 16, RT = 4;
    __shared__ float As[BK][BM + 4];   // +4 keeps 16B row alignment
    __shared__ float Bs[BK][BN + 4];
    const int tid = threadIdx.x;
    const int tn = tid >> 4;   // 0..15 (wave-local: 4 values -> conflict-free Bs)
    const int tm = tid & 15;   // 0..15
    const int m0 = blockIdx.x * BM;
    const int n0 = blockIdx.y * BN;

    float acc[RT][NT];
#pragma unroll
    for (int r = 0; r < RT; ++r)
#pragma unroll
        for (int c = 0; c < NT; ++c) acc[r][c] = 0.f;

    const int sa_m = tid >> 2;          // 0..63
    const int sa_k = (tid & 3) << 2;    // 0,4,8,12
    constexpr int BITER = (BK * BN) / (4 * 256);  // 1 (BN=64) or 2 (BN=128)

    for (int k0 = 0; k0 < K; k0 += BK) {
        // issue global loads
        const float4 av = *(const float4*)(A + (size_t)(m0 + sa_m) * K + k0 + sa_k);
        float4 bv[BITER];
#pragma unroll
        for (int i = 0; i < BITER; ++i) {
            const int f  = tid + i * 256;
            const int kl = f / (BN / 4);
            const int n4 = f % (BN / 4);
            bv[i] = *(const float4*)(Wt + (size_t)(k0 + kl) * N + n0 + n4 * 4);
        }
        __syncthreads();   // previous iteration's LDS reads done
        As[sa_k + 0][sa_m] = av.x;
        As[sa_k + 1][sa_m] = av.y;
        As[sa_k + 2][sa_m] = av.z;
        As[sa_k + 3][sa_m] = av.w;
#pragma unroll
        for (int i = 0; i < BITER; ++i) {
            const int f  = tid + i * 256;
            const int kl = f / (BN / 4);
            const int n4 = f % (BN / 4);
            *(float4*)&Bs[kl][n4 * 4] = bv[i];
        }
        __syncthreads();
#pragma unroll
        for (int kk = 0; kk < BK; ++kk) {
            const float4 a4 = *(const float4*)&As[kk][tm * RT];
            float b[NT];
#pragma unroll
            for (int c4 = 0; c4 < NT / 4; ++c4) {
                float4 t = *(const float4*)&Bs[kk][tn * NT + c4 * 4];
                b[c4 * 4 + 0] = t.x; b[c4 * 4 + 1] = t.y;
                b[c4 * 4 + 2] = t.z; b[c4 * 4 + 3] = t.w;
            }
#pragma unroll
            for (int c = 0; c < NT; ++c) {
                acc[0][c] = fmaf(a4.x, b[c], acc[0][c]);
                acc[1][c] = fmaf(a4.y, b[c], acc[1][c]);
                acc[2][c] = fmaf(a4.z, b[c], acc[2][c]);
                acc[3][c] = fmaf(a4.w, b[c], acc[3][c]);
            }
        }
    }

    // epilogue: bias, qscale, store
#pragma unroll
    for (int c = 0; c < NT; ++c) {
        const int n = n0 + tn * NT + c;
        const float bz = bias[n];
        const float sc = (n < qcols) ? qscale : 1.f;
#pragma unroll
        for (int r = 0; r < RT; ++r) acc[r][c] = (acc[r][c] + bz) * sc;
    }
    if (TRANS) {
#pragma unroll
        for (int c = 0; c < NT; ++c) {
            const int n = n0 + tn * NT + c;
            *(float4*)(out + (size_t)n * M + m0 + tm * RT) =
                make_float4(acc[0][c], acc[1][c], acc[2][c], acc[3][c]);
        }
    } else {
#pragma unroll
        for (int r = 0; r < RT; ++r) {
            float* op = out + (size_t)(m0 + tm * RT + r) * N + n0 + tn * NT;
#pragma unroll
            for (int c4 = 0; c4 < NT / 4; ++c4)
                *(float4*)(op + c4 * 4) = make_float4(acc[r][c4 * 4], acc[r][c4 * 4 + 1],
                                                      acc[r][c4 * 4 + 2], acc[r][c4 * 4 + 3]);
        }
    }
}

template <int VPL>
__device__ inline void loadv(const float* __restrict__ p, float* d) {
    if constexpr (VPL == 2) {
        float2 t = *(const float2*)p;
        d[0] = t.x; d[1] = t.y;
    } else if constexpr (VPL == 4) {
        float4 t = *(const float4*)p;
        d[0] = t.x; d[1] = t.y; d[2] = t.z; d[3] = t.w;
    } else {
        float4 t0 = *(const float4*)p;
        float4 t1 = *(const float4*)(p + 4);
        d[0] = t0.x; d[1] = t0.y; d[2] = t0.z; d[3] = t0.w;
        d[4] = t1.x; d[5] = t1.y; d[6] = t1.z; d[7] = t1.w;
    }
}

// Neighborhood attention, 4 pixels per wave (16-lane channel groups).
template <int C>
__global__ __launch_bounds__(256) void na2d_attn_v3(
        const float* __restrict__ qkv, const float* __restrict__ rpb,
        float* __restrict__ out, int H, int W) {
    constexpr int VPL = C / 16;  // 2 / 4 / 8
    const int lane = threadIdx.x & 63;
    const int g    = lane >> 4;
    const int li   = lane & 15;
    const int wave = threadIdx.x >> 6;
    const int pix  = (blockIdx.x * 4 + wave) * 4 + g;
    const int h = pix / W;
    const int w = pix - h * W;
    const int h0 = min(max(h - 2, 0), H - 5);
    const int w0 = min(max(w - 2, 0), W - 5);
    const int cb = li * VPL;

    float qf[VPL];
    loadv<VPL>(qkv + (size_t)pix * (3 * C) + cb, qf);

    float p[25];
#pragma unroll
    for (int j = 0; j < 25; ++j) {
        const int nh = h0 + j / 5;
        const int nw = w0 + j % 5;
        float kf[VPL];
        loadv<VPL>(qkv + (size_t)(nh * W + nw) * (3 * C) + C + cb, kf);
        float s = qf[0] * kf[0];
#pragma unroll
        for (int v = 1; v < VPL; ++v) s = fmaf(qf[v], kf[v], s);
        p[j] = s;
    }
#pragma unroll
    for (int j = 0; j < 25; ++j) {
        float v = p[j];
        v += __shfl_xor(v, 1);
        v += __shfl_xor(v, 2);
        v += __shfl_xor(v, 4);
        v += __shfl_xor(v, 8);
        const int nh = h0 + j / 5;
        const int nw = w0 + j % 5;
        p[j] = v + rpb[(nh - h + 4) * 9 + (nw - w + 4)];
    }
    float mx = p[0];
#pragma unroll
    for (int j = 1; j < 25; ++j) mx = fmaxf(mx, p[j]);
    float sum = 0.f;
#pragma unroll
    for (int j = 0; j < 25; ++j) {
        p[j] = expf(p[j] - mx);
        sum += p[j];
    }
    const float inv = 1.f / sum;

    float a[VPL];
#pragma unroll
    for (int v = 0; v < VPL; ++v) a[v] = 0.f;
#pragma unroll
    for (int j = 0; j < 25; ++j) {
        const int nh = h0 + j / 5;
        const int nw = w0 + j % 5;
        float vf[VPL];
        loadv<VPL>(qkv + (size_t)(nh * W + nw) * (3 * C) + 2 * C + cb, vf);
#pragma unroll
        for (int v = 0; v < VPL; ++v) a[v] = fmaf(p[j], vf[v], a[v]);
    }
    float* op = out + (size_t)pix * C + cb;
    if constexpr (VPL == 2) {
        *(float2*)op = make_float2(a[0] * inv, a[1] * inv);
    } else if constexpr (VPL == 4) {
        *(float4*)op = make_float4(a[0] * inv, a[1] * inv, a[2] * inv, a[3] * inv);
    } else {
        *(float4*)op       = make_float4(a[0] * inv, a[1] * inv, a[2] * inv, a[3] * inv);
        *(float4*)(op + 4) = make_float4(a[4] * inv, a[5] * inv, a[6] * inv, a[7] * inv);
    }
}

// Bilinear 2x upsample only: (Hs,Ws,C) -> (2Hs,2Ws,C), float4 channels.
template <int C>
__global__ void up2x_only(const float* __restrict__ y, float* __restrict__ out,
                          int Hs, int Ws) {
    constexpr int C4 = C / 4;
    const int Hd = 2 * Hs, Wd = 2 * Ws;
    const int idx = blockIdx.x * blockDim.x + threadIdx.x;
    if (idx >= Hd * Wd * C4) return;
    const int c4  = idx % C4;
    const int pix = idx / C4;
    const int w2  = pix % Wd;
    const int h2  = pix / Wd;
    const float ph = (float)h2 * (float)(Hs - 1) / (float)(Hd - 1);
    const int h0i = (int)ph;
    const int h1i = min(h0i + 1, Hs - 1);
    const float wh = ph - (float)h0i;
    const float pw = (float)w2 * (float)(Ws - 1) / (float)(Wd - 1);
    const int w0i = (int)pw;
    const int w1i = min(w0i + 1, Ws - 1);
    const float ww = pw - (float)w0i;
    const float4 v00 = *(const float4*)(y + ((size_t)h0i * Ws + w0i) * C + c4 * 4);
    const float4 v01 = *(const float4*)(y + ((size_t)h0i * Ws + w1i) * C + c4 * 4);
    const float4 v10 = *(const float4*)(y + ((size_t)h1i * Ws + w0i) * C + c4 * 4);
    const float4 v11 = *(const float4*)(y + ((size_t)h1i * Ws + w1i) * C + c4 * 4);
    float4 r;
    r.x = (v00.x * (1.f - wh) + v10.x * wh) * (1.f - ww) + (v01.x * (1.f - wh) + v11.x * wh) * ww;
    r.y = (v00.y * (1.f - wh) + v10.y * wh) * (1.f - ww) + (v01.y * (1.f - wh) + v11.y * wh) * ww;
    r.z = (v00.z * (1.f - wh) + v10.z * wh) * (1.f - ww) + (v01.z * (1.f - wh) + v11.z * wh) * ww;
    r.w = (v00.w * (1.f - wh) + v10.w * wh) * (1.f - ww) + (v01.w * (1.f - wh) + v11.w * wh) * ww;
    *(float4*)(out + (size_t)pix * C + c4 * 4) = r;
}

extern "C" void kernel_launch(void* const* d_in, const int* in_sizes, int n_in,
                              void* d_out, int out_size, void* d_ws, size_t ws_size,
                              hipStream_t stream) {
    const float* attn    = (const float*)d_in[0];
    const float* w_qkv1  = (const float*)d_in[1];
    const float* b_qkv1  = (const float*)d_in[2];
    const float* w_proj1 = (const float*)d_in[3];
    const float* b_proj1 = (const float*)d_in[4];
    const float* rpb1    = (const float*)d_in[5];
    const float* w_qkv2  = (const float*)d_in[6];
    const float* b_qkv2  = (const float*)d_in[7];
    const float* w_proj2 = (const float*)d_in[8];
    const float* b_proj2 = (const float*)d_in[9];
    const float* rpb2    = (const float*)d_in[10];
    const float* w_qkv3  = (const float*)d_in[11];
    const float* b_qkv3  = (const float*)d_in[12];
    const float* w_proj3 = (const float*)d_in[13];
    const float* b_proj3 = (const float*)d_in[14];
    const float* rpb3    = (const float*)d_in[15];
    const float* w_up1   = (const float*)d_in[16];
    const float* b_up1   = (const float*)d_in[17];
    const float* w_up2   = (const float*)d_in[18];
    const float* b_up2   = (const float*)d_in[19];
    float* out = (float*)d_out;

    float* ws   = (float*)d_ws;
    float* bufA = ws;                        // x (HWC)   (max 18432*128)
    float* bufB = bufA + 2359296;            // qkv       (max 18432*384)
    float* bufC = bufB + 7077888;            // attn out / up2x scratch
    float* bufD = bufC + 2359296;            // y (proj out, max 4608*64)

    // ---- Stage 1: C=32, 24x48 ----
    {
        const int H = 24, W = 48, C = 32, M = H * W;
        chw_to_hwc<<<(C * M + 255) / 256, 256, 0, stream>>>(attn, bufA, C, M);
        mm_bias<16><<<M / 16, 3 * C, 16 * C * 4, stream>>>(
            bufA, w_qkv1, b_qkv1, bufB, M, C, 3 * C, C, 1.f / sqrtf((float)C));
        na2d_attn_v3<32><<<M / 16, 256, 0, stream>>>(bufB, rpb1, bufC, H, W);
        mm_bias<16><<<M / 16, C, 16 * C * 4, stream>>>(
            bufC, w_proj1, b_proj1, bufD, M, C, C, 0, 1.f);
        up2x_only<32><<<(4 * M * 8 + 255) / 256, 256, 0, stream>>>(bufD, bufC, H, W);
        gemm_rt<64, 4, 0><<<dim3(4 * M / 64, 1), 256, 0, stream>>>(
            bufC, w_up1, b_up1, bufA, 4 * M, C, 64, 0, 1.f);
    }
    // ---- Stage 2: C=64, 48x96 ----
    {
        const int H = 48, W = 96, C = 64, M = H * W;
        gemm_rt<64, 4, 0><<<dim3(M / 64, 3), 256, 0, stream>>>(
            bufA, w_qkv2, b_qkv2, bufB, M, C, 3 * C, C, 1.f / sqrtf((float)C));
        na2d_attn_v3<64><<<M / 16, 256, 0, stream>>>(bufB, rpb2, bufC, H, W);
        gemm_rt<64, 4, 0><<<dim3(M / 64, 1), 256, 0, stream>>>(
            bufC, w_proj2, b_proj2, bufD, M, C, C, 0, 1.f);
        up2x_only<64><<<(4 * M * 16 + 255) / 256, 256, 0, stream>>>(bufD, bufC, H, W);
        gemm_rt<128, 8, 0><<<dim3(4 * M / 64, 1), 256, 0, stream>>>(
            bufC, w_up2, b_up2, bufA, 4 * M, C, 128, 0, 1.f);
    }
    // ---- Stage 3: C=128, 96x192 ----
    {
        const int H = 96, W = 192, C = 128, M = H * W;
        gemm_rt<128, 8, 0><<<dim3(M / 64, 3), 256, 0, stream>>>(
            bufA, w_qkv3, b_qkv3, bufB, M, C, 3 * C, C, 1.f / sqrtf((float)C));
        na2d_attn_v3<128><<<M / 16, 256, 0, stream>>>(bufB, rpb3, bufC, H, W);
        gemm_rt<128, 8, 1><<<dim3(M / 64, 1), 256, 0, stream>>>(
            bufC, w_proj3, b_proj3, out, M, C, C, 0, 1.f);  // -> CHW
    }
}

// Round 8
// 155.259 us; speedup vs baseline: 2.8761x; 1.1763x over previous
//
#include <hip/hip_runtime.h>
#include <math.h>

// ---------------------------------------------------------------------------
// Refine_Attn: 3-level neighborhood-attention pyramid, fp32.
// Stage 1: C=32,  H=24, W=48 | Stage 2: C=64, H=48, W=96 | Stage 3: C=128, 96x192
// k=5 neighborhood, rpb bias (9x9), softmax over 25, proj, bilinear up2x.
// ---------------------------------------------------------------------------

// Transpose (C,H*W) -> (H*W,C)
__global__ void chw_to_hwc(const float* __restrict__ in, float* __restrict__ out,
                           int C, int HW) {
    int idx = blockIdx.x * blockDim.x + threadIdx.x;
    if (idx >= C * HW) return;
    int hw = idx / C;
    int c  = idx - hw * C;
    out[idx] = in[c * HW + hw];
}

// Small-matrix fallback (stage 1 only). out[m][n]=sum_k A[m][k]*Wt[k][n]+bias[n].
template <int MT>
__global__ void mm_bias(const float* __restrict__ A, const float* __restrict__ Wt,
                        const float* __restrict__ bias, float* __restrict__ out,
                        int M, int K, int N, int qcols, float qscale) {
    extern __shared__ float As[];  // MT*K floats
    const int m0 = blockIdx.x * MT;
    const int n  = threadIdx.x;
    {
        const float4* src = (const float4*)(A + (size_t)m0 * K);
        float4* dst = (float4*)As;
        for (int idx = n; idx < MT * K / 4; idx += blockDim.x) dst[idx] = src[idx];
    }
    __syncthreads();

    float acc[MT];
#pragma unroll
    for (int r = 0; r < MT; ++r) acc[r] = bias[n];
    for (int k = 0; k < K; k += 4) {
        const float* wp = Wt + (size_t)k * N + n;
        const float w0 = wp[0];
        const float w1 = wp[N];
        const float w2 = wp[2 * N];
        const float w3 = wp[3 * N];
#pragma unroll
        for (int r = 0; r < MT; ++r) {
            float4 a4 = *(const float4*)&As[r * K + k];
            acc[r] = fmaf(a4.x, w0, acc[r]);
            acc[r] = fmaf(a4.y, w1, acc[r]);
            acc[r] = fmaf(a4.z, w2, acc[r]);
            acc[r] = fmaf(a4.w, w3, acc[r]);
        }
    }
    if (n < qcols) {
#pragma unroll
        for (int r = 0; r < MT; ++r) acc[r] *= qscale;
    }
#pragma unroll
    for (int r = 0; r < MT; ++r) out[(size_t)(m0 + r) * N + n] = acc[r];
}

// Register-tiled GEMM: out = A(M,K) @ Wt(K,N) + bias; first qcols cols scaled
// by qscale after bias. Block tile 64 x BN, BK=16, 256 threads, thread tile
// 4 x NT (BN/NT must be 16). TRANS: out[n][m] (CHW). M%64==0, K%16==0, N%BN==0.
template <int BN, int NT, int TRANS>
__global__ __launch_bounds__(256) void gemm_rt(
        const float* __restrict__ A, const float* __restrict__ Wt,
        const float* __restrict__ bias, float* __restrict__ out,
        int M, int K, int N, int qcols, float qscale) {
    constexpr int BM = 64, BK = 16, RT = 4;
    __shared__ float As[BK][BM + 4];   // +4 keeps 16B row alignment
    __shared__ float Bs[BK][BN + 4];
    const int tid = threadIdx.x;
    const int tn = tid >> 4;   // 0..15
    const int tm = tid & 15;   // 0..15
    const int m0 = blockIdx.x * BM;
    const int n0 = blockIdx.y * BN;

    float acc[RT][NT];
#pragma unroll
    for (int r = 0; r < RT; ++r)
#pragma unroll
        for (int c = 0; c < NT; ++c) acc[r][c] = 0.f;

    const int sa_m = tid >> 2;          // 0..63
    const int sa_k = (tid & 3) << 2;    // 0,4,8,12
    constexpr int BITER = (BK * BN) / (4 * 256);  // 1 (BN=64) or 2 (BN=128)

    for (int k0 = 0; k0 < K; k0 += BK) {
        const float4 av = *(const float4*)(A + (size_t)(m0 + sa_m) * K + k0 + sa_k);
        float4 bv[BITER];
#pragma unroll
        for (int i = 0; i < BITER; ++i) {
            const int f  = tid + i * 256;
            const int kl = f / (BN / 4);
            const int n4 = f % (BN / 4);
            bv[i] = *(const float4*)(Wt + (size_t)(k0 + kl) * N + n0 + n4 * 4);
        }
        __syncthreads();
        As[sa_k + 0][sa_m] = av.x;
        As[sa_k + 1][sa_m] = av.y;
        As[sa_k + 2][sa_m] = av.z;
        As[sa_k + 3][sa_m] = av.w;
#pragma unroll
        for (int i = 0; i < BITER; ++i) {
            const int f  = tid + i * 256;
            const int kl = f / (BN / 4);
            const int n4 = f % (BN / 4);
            *(float4*)&Bs[kl][n4 * 4] = bv[i];
        }
        __syncthreads();
#pragma unroll
        for (int kk = 0; kk < BK; ++kk) {
            const float4 a4 = *(const float4*)&As[kk][tm * RT];
            float b[NT];
#pragma unroll
            for (int c4 = 0; c4 < NT / 4; ++c4) {
                float4 t = *(const float4*)&Bs[kk][tn * NT + c4 * 4];
                b[c4 * 4 + 0] = t.x; b[c4 * 4 + 1] = t.y;
                b[c4 * 4 + 2] = t.z; b[c4 * 4 + 3] = t.w;
            }
#pragma unroll
            for (int c = 0; c < NT; ++c) {
                acc[0][c] = fmaf(a4.x, b[c], acc[0][c]);
                acc[1][c] = fmaf(a4.y, b[c], acc[1][c]);
                acc[2][c] = fmaf(a4.z, b[c], acc[2][c]);
                acc[3][c] = fmaf(a4.w, b[c], acc[3][c]);
            }
        }
    }

#pragma unroll
    for (int c = 0; c < NT; ++c) {
        const int n = n0 + tn * NT + c;
        const float bz = bias[n];
        const float sc = (n < qcols) ? qscale : 1.f;
#pragma unroll
        for (int r = 0; r < RT; ++r) acc[r][c] = (acc[r][c] + bz) * sc;
    }
    if (TRANS) {
#pragma unroll
        for (int c = 0; c < NT; ++c) {
            const int n = n0 + tn * NT + c;
            *(float4*)(out + (size_t)n * M + m0 + tm * RT) =
                make_float4(acc[0][c], acc[1][c], acc[2][c], acc[3][c]);
        }
    } else {
#pragma unroll
        for (int r = 0; r < RT; ++r) {
            float* op = out + (size_t)(m0 + tm * RT + r) * N + n0 + tn * NT;
#pragma unroll
            for (int c4 = 0; c4 < NT / 4; ++c4)
                *(float4*)(op + c4 * 4) = make_float4(acc[r][c4 * 4], acc[r][c4 * 4 + 1],
                                                      acc[r][c4 * 4 + 2], acc[r][c4 * 4 + 3]);
        }
    }
}

template <int VPL>
__device__ inline void loadv(const float* __restrict__ p, float* d) {
    if constexpr (VPL == 2) {
        float2 t = *(const float2*)p;
        d[0] = t.x; d[1] = t.y;
    } else if constexpr (VPL == 4) {
        float4 t = *(const float4*)p;
        d[0] = t.x; d[1] = t.y; d[2] = t.z; d[3] = t.w;
    } else {
        float4 t0 = *(const float4*)p;
        float4 t1 = *(const float4*)(p + 4);
        d[0] = t0.x; d[1] = t0.y; d[2] = t0.z; d[3] = t0.w;
        d[4] = t1.x; d[5] = t1.y; d[6] = t1.z; d[7] = t1.w;
    }
}

// Neighborhood attention v4: 4 pixels per wave (16-lane channel groups),
// neighbor loads batched 5-at-a-time (one kernel row per batch) so 10
// global_load_dwordx4 are in flight per batch instead of serialized
// load->use per neighbor (v3 was latency-serialized: VALUBusy 15%).
template <int C>
__global__ __launch_bounds__(256) void na2d_attn_v4(
        const float* __restrict__ qkv, const float* __restrict__ rpb,
        float* __restrict__ out, int H, int W) {
    constexpr int VPL = C / 16;  // 2 / 4 / 8
    const int lane = threadIdx.x & 63;
    const int g    = lane >> 4;
    const int li   = lane & 15;
    const int wave = threadIdx.x >> 6;
    const int pix  = (blockIdx.x * 4 + wave) * 4 + g;
    const int h = pix / W;
    const int w = pix - h * W;
    const int h0 = min(max(h - 2, 0), H - 5);
    const int w0 = min(max(w - 2, 0), W - 5);
    const int cb = li * VPL;
    const int bih = h0 - h + 4;   // rpb row offset base
    const int biw = w0 - w + 4;   // rpb col offset base

    float qf[VPL];
    loadv<VPL>(qkv + (size_t)pix * (3 * C) + cb, qf);

    // ---- QK^T: row-batched loads (5 neighbors in flight per batch) ----
    float p[25];
#pragma unroll
    for (int jr = 0; jr < 5; ++jr) {
        const float* rowk = qkv + (size_t)((h0 + jr) * W + w0) * (3 * C) + C + cb;
        float kf[5][VPL];
#pragma unroll
        for (int jc = 0; jc < 5; ++jc) loadv<VPL>(rowk + jc * 3 * C, kf[jc]);
#pragma unroll
        for (int jc = 0; jc < 5; ++jc) {
            float s = qf[0] * kf[jc][0];
#pragma unroll
            for (int v = 1; v < VPL; ++v) s = fmaf(qf[v], kf[jc][v], s);
            p[jr * 5 + jc] = s;
        }
    }

    // 16-lane butterfly + rpb bias
#pragma unroll
    for (int jr = 0; jr < 5; ++jr)
#pragma unroll
        for (int jc = 0; jc < 5; ++jc) {
            const int j = jr * 5 + jc;
            float v = p[j];
            v += __shfl_xor(v, 1);
            v += __shfl_xor(v, 2);
            v += __shfl_xor(v, 4);
            v += __shfl_xor(v, 8);
            p[j] = v + rpb[(bih + jr) * 9 + (biw + jc)];
        }

    // softmax over 25 (registers, redundant per lane)
    float mx = p[0];
#pragma unroll
    for (int j = 1; j < 25; ++j) mx = fmaxf(mx, p[j]);
    float sum = 0.f;
#pragma unroll
    for (int j = 0; j < 25; ++j) {
        p[j] = expf(p[j] - mx);
        sum += p[j];
    }
    const float inv = 1.f / sum;

    // ---- PV: row-batched loads ----
    float a[VPL];
#pragma unroll
    for (int v = 0; v < VPL; ++v) a[v] = 0.f;
#pragma unroll
    for (int jr = 0; jr < 5; ++jr) {
        const float* rowv = qkv + (size_t)((h0 + jr) * W + w0) * (3 * C) + 2 * C + cb;
        float vf[5][VPL];
#pragma unroll
        for (int jc = 0; jc < 5; ++jc) loadv<VPL>(rowv + jc * 3 * C, vf[jc]);
#pragma unroll
        for (int jc = 0; jc < 5; ++jc)
#pragma unroll
            for (int v = 0; v < VPL; ++v) a[v] = fmaf(p[jr * 5 + jc], vf[jc][v], a[v]);
    }

    float* op = out + (size_t)pix * C + cb;
    if constexpr (VPL == 2) {
        *(float2*)op = make_float2(a[0] * inv, a[1] * inv);
    } else if constexpr (VPL == 4) {
        *(float4*)op = make_float4(a[0] * inv, a[1] * inv, a[2] * inv, a[3] * inv);
    } else {
        *(float4*)op       = make_float4(a[0] * inv, a[1] * inv, a[2] * inv, a[3] * inv);
        *(float4*)(op + 4) = make_float4(a[4] * inv, a[5] * inv, a[6] * inv, a[7] * inv);
    }
}

// Bilinear 2x upsample only: (Hs,Ws,C) -> (2Hs,2Ws,C), float4 channels.
template <int C>
__global__ void up2x_only(const float* __restrict__ y, float* __restrict__ out,
                          int Hs, int Ws) {
    constexpr int C4 = C / 4;
    const int Hd = 2 * Hs, Wd = 2 * Ws;
    const int idx = blockIdx.x * blockDim.x + threadIdx.x;
    if (idx >= Hd * Wd * C4) return;
    const int c4  = idx % C4;
    const int pix = idx / C4;
    const int w2  = pix % Wd;
    const int h2  = pix / Wd;
    const float ph = (float)h2 * (float)(Hs - 1) / (float)(Hd - 1);
    const int h0i = (int)ph;
    const int h1i = min(h0i + 1, Hs - 1);
    const float wh = ph - (float)h0i;
    const float pw = (float)w2 * (float)(Ws - 1) / (float)(Wd - 1);
    const int w0i = (int)pw;
    const int w1i = min(w0i + 1, Ws - 1);
    const float ww = pw - (float)w0i;
    const float4 v00 = *(const float4*)(y + ((size_t)h0i * Ws + w0i) * C + c4 * 4);
    const float4 v01 = *(const float4*)(y + ((size_t)h0i * Ws + w1i) * C + c4 * 4);
    const float4 v10 = *(const float4*)(y + ((size_t)h1i * Ws + w0i) * C + c4 * 4);
    const float4 v11 = *(const float4*)(y + ((size_t)h1i * Ws + w1i) * C + c4 * 4);
    float4 r;
    r.x = (v00.x * (1.f - wh) + v10.x * wh) * (1.f - ww) + (v01.x * (1.f - wh) + v11.x * wh) * ww;
    r.y = (v00.y * (1.f - wh) + v10.y * wh) * (1.f - ww) + (v01.y * (1.f - wh) + v11.y * wh) * ww;
    r.z = (v00.z * (1.f - wh) + v10.z * wh) * (1.f - ww) + (v01.z * (1.f - wh) + v11.z * wh) * ww;
    r.w = (v00.w * (1.f - wh) + v10.w * wh) * (1.f - ww) + (v01.w * (1.f - wh) + v11.w * wh) * ww;
    *(float4*)(out + (size_t)pix * C + c4 * 4) = r;
}

extern "C" void kernel_launch(void* const* d_in, const int* in_sizes, int n_in,
                              void* d_out, int out_size, void* d_ws, size_t ws_size,
                              hipStream_t stream) {
    const float* attn    = (const float*)d_in[0];
    const float* w_qkv1  = (const float*)d_in[1];
    const float* b_qkv1  = (const float*)d_in[2];
    const float* w_proj1 = (const float*)d_in[3];
    const float* b_proj1 = (const float*)d_in[4];
    const float* rpb1    = (const float*)d_in[5];
    const float* w_qkv2  = (const float*)d_in[6];
    const float* b_qkv2  = (const float*)d_in[7];
    const float* w_proj2 = (const float*)d_in[8];
    const float* b_proj2 = (const float*)d_in[9];
    const float* rpb2    = (const float*)d_in[10];
    const float* w_qkv3  = (const float*)d_in[11];
    const float* b_qkv3  = (const float*)d_in[12];
    const float* w_proj3 = (const float*)d_in[13];
    const float* b_proj3 = (const float*)d_in[14];
    const float* rpb3    = (const float*)d_in[15];
    const float* w_up1   = (const float*)d_in[16];
    const float* b_up1   = (const float*)d_in[17];
    const float* w_up2   = (const float*)d_in[18];
    const float* b_up2   = (const float*)d_in[19];
    float* out = (float*)d_out;

    float* ws   = (float*)d_ws;
    float* bufA = ws;                        // x (HWC)   (max 18432*128)
    float* bufB = bufA + 2359296;            // qkv       (max 18432*384)
    float* bufC = bufB + 7077888;            // attn out / up2x scratch
    float* bufD = bufC + 2359296;            // y (proj out, max 4608*64)

    // ---- Stage 1: C=32, 24x48 ----
    {
        const int H = 24, W = 48, C = 32, M = H * W;
        chw_to_hwc<<<(C * M + 255) / 256, 256, 0, stream>>>(attn, bufA, C, M);
        mm_bias<16><<<M / 16, 3 * C, 16 * C * 4, stream>>>(
            bufA, w_qkv1, b_qkv1, bufB, M, C, 3 * C, C, 1.f / sqrtf((float)C));
        na2d_attn_v4<32><<<M / 16, 256, 0, stream>>>(bufB, rpb1, bufC, H, W);
        mm_bias<16><<<M / 16, C, 16 * C * 4, stream>>>(
            bufC, w_proj1, b_proj1, bufD, M, C, C, 0, 1.f);
        up2x_only<32><<<(4 * M * 8 + 255) / 256, 256, 0, stream>>>(bufD, bufC, H, W);
        gemm_rt<64, 4, 0><<<dim3(4 * M / 64, 1), 256, 0, stream>>>(
            bufC, w_up1, b_up1, bufA, 4 * M, C, 64, 0, 1.f);
    }
    // ---- Stage 2: C=64, 48x96 ----
    {
        const int H = 48, W = 96, C = 64, M = H * W;
        gemm_rt<64, 4, 0><<<dim3(M / 64, 3), 256, 0, stream>>>(
            bufA, w_qkv2, b_qkv2, bufB, M, C, 3 * C, C, 1.f / sqrtf((float)C));
        na2d_attn_v4<64><<<M / 16, 256, 0, stream>>>(bufB, rpb2, bufC, H, W);
        gemm_rt<64, 4, 0><<<dim3(M / 64, 1), 256, 0, stream>>>(
            bufC, w_proj2, b_proj2, bufD, M, C, C, 0, 1.f);
        up2x_only<64><<<(4 * M * 16 + 255) / 256, 256, 0, stream>>>(bufD, bufC, H, W);
        gemm_rt<128, 8, 0><<<dim3(4 * M / 64, 1), 256, 0, stream>>>(
            bufC, w_up2, b_up2, bufA, 4 * M, C, 128, 0, 1.f);
    }
    // ---- Stage 3: C=128, 96x192 ----
    {
        const int H = 96, W = 192, C = 128, M = H * W;
        gemm_rt<128, 8, 0><<<dim3(M / 64, 3), 256, 0, stream>>>(
            bufA, w_qkv3, b_qkv3, bufB, M, C, 3 * C, C, 1.f / sqrtf((float)C));
        na2d_attn_v4<128><<<M / 16, 256, 0, stream>>>(bufB, rpb3, bufC, H, W);
        gemm_rt<128, 8, 1><<<dim3(M / 64, 1), 256, 0, stream>>>(
            bufC, w_proj3, b_proj3, out, M, C, C, 0, 1.f);  // -> CHW
    }
}

// Round 11
// 151.111 us; speedup vs baseline: 2.9551x; 1.0275x over previous
//
#include <hip/hip_runtime.h>
#include <math.h>

// ---------------------------------------------------------------------------
// Refine_Attn: 3-level neighborhood-attention pyramid, fp32.
// Stage 1: C=32,  H=24, W=48 | Stage 2: C=64, H=48, W=96 | Stage 3: C=128, 96x192
// k=5 neighborhood, rpb bias (9x9), softmax over 25, proj, bilinear up2x.
// Launch plan (11 dispatches):
//  S1: qkv1(CHW-gather mm) -> na2d -> proj1(mm) -> up2x+upproj GEMM (fused)
//  S2: qkv2 GEMM -> na2d -> proj2 GEMM -> up2x+upproj GEMM (fused)
//  S3: qkv3 GEMM -> na2d -> proj3 GEMM (writes CHW)
// ---------------------------------------------------------------------------

// Small-matrix broadcast matmul (stage 1 only).
// CHW: A is (K, HW) and we gather A[m][k] = A[k*HW+m] during staging.
template <int MT, int CHW>
__global__ void mm_bias(const float* __restrict__ A, const float* __restrict__ Wt,
                        const float* __restrict__ bias, float* __restrict__ out,
                        int M, int K, int N, int qcols, float qscale) {
    extern __shared__ float As[];  // MT*K floats
    const int m0 = blockIdx.x * MT;
    const int n  = threadIdx.x;
    if (CHW) {
        for (int idx = n; idx < MT * K; idx += blockDim.x) {
            const int r = idx / K;
            const int k = idx - r * K;
            As[idx] = A[(size_t)k * M + m0 + r];   // gather from (K,M)
        }
    } else {
        const float4* src = (const float4*)(A + (size_t)m0 * K);
        float4* dst = (float4*)As;
        for (int idx = n; idx < MT * K / 4; idx += blockDim.x) dst[idx] = src[idx];
    }
    __syncthreads();

    float acc[MT];
#pragma unroll
    for (int r = 0; r < MT; ++r) acc[r] = bias[n];
    for (int k = 0; k < K; k += 4) {
        const float* wp = Wt + (size_t)k * N + n;
        const float w0 = wp[0];
        const float w1 = wp[N];
        const float w2 = wp[2 * N];
        const float w3 = wp[3 * N];
#pragma unroll
        for (int r = 0; r < MT; ++r) {
            float4 a4 = *(const float4*)&As[r * K + k];
            acc[r] = fmaf(a4.x, w0, acc[r]);
            acc[r] = fmaf(a4.y, w1, acc[r]);
            acc[r] = fmaf(a4.z, w2, acc[r]);
            acc[r] = fmaf(a4.w, w3, acc[r]);
        }
    }
    if (n < qcols) {
#pragma unroll
        for (int r = 0; r < MT; ++r) acc[r] *= qscale;
    }
#pragma unroll
    for (int r = 0; r < MT; ++r) out[(size_t)(m0 + r) * N + n] = acc[r];
}

// Register-tiled GEMM: out = A(M,K) @ Wt(K,N) + bias; first qcols cols scaled
// by qscale after bias. Block tile BM x BN (BM in {64,128}), BK=16, 256 thr,
// thread tile RT x NT with RT=BM/16, BN=16*NT. TRANS: out[n][m] (CHW).
// UP: A is the bilinear 2x-upsample of y (Hs,Ws,K) evaluated on the fly
// (A row m = output pixel m of the (2Hs,2Ws) grid).
// Requires M%BM==0, K%16==0, N%BN==0.
template <int BM, int BN, int NT, int TRANS, int UP>
__global__ __launch_bounds__(256) void gemm_rt(
        const float* __restrict__ A, const float* __restrict__ Wt,
        const float* __restrict__ bias, float* __restrict__ out,
        int M, int K, int N, int qcols, float qscale, int Hs, int Ws) {
    constexpr int BK = 16;
    constexpr int RT = BM / 16;
    constexpr int AIT = (BM * BK) / (4 * 256);  // float4 A-stages per thread: 1|2
    constexpr int BIT = (BK * BN) / (4 * 256);  // float4 B-stages per thread: 1|2
    __shared__ float As[BK][BM + 4];
    __shared__ float Bs[BK][BN + 4];
    const int tid = threadIdx.x;
    const int tn = tid >> 4;   // 0..15
    const int tm = tid & 15;   // 0..15
    const int m0 = blockIdx.x * BM;
    const int n0 = blockIdx.y * BN;

    const int sa_m = tid >> 2;          // 0..63 (+64 per AIT step)
    const int sa_k = (tid & 3) << 2;    // 0,4,8,12

    // UP mode: precompute bilinear sources/weights for this thread's rows
    const float* ybase[AIT][4];
    float uwh[AIT], uww[AIT];
    if (UP) {
        const int Wd = 2 * Ws, Hd = 2 * Hs;
#pragma unroll
        for (int i = 0; i < AIT; ++i) {
            const int row = m0 + sa_m + i * 64;   // output pixel
            const int h2 = row / Wd;
            const int w2 = row - h2 * Wd;
            const float ph = (float)h2 * (float)(Hs - 1) / (float)(Hd - 1);
            const int h0i = (int)ph;
            const int h1i = min(h0i + 1, Hs - 1);
            uwh[i] = ph - (float)h0i;
            const float pw = (float)w2 * (float)(Ws - 1) / (float)(Wd - 1);
            const int w0i = (int)pw;
            const int w1i = min(w0i + 1, Ws - 1);
            uww[i] = pw - (float)w0i;
            ybase[i][0] = A + ((size_t)h0i * Ws + w0i) * K;
            ybase[i][1] = A + ((size_t)h0i * Ws + w1i) * K;
            ybase[i][2] = A + ((size_t)h1i * Ws + w0i) * K;
            ybase[i][3] = A + ((size_t)h1i * Ws + w1i) * K;
        }
    }

    float acc[RT][NT];
#pragma unroll
    for (int r = 0; r < RT; ++r)
#pragma unroll
        for (int c = 0; c < NT; ++c) acc[r][c] = 0.f;

    for (int k0 = 0; k0 < K; k0 += BK) {
        float4 av[AIT];
#pragma unroll
        for (int i = 0; i < AIT; ++i) {
            if (UP) {
                const float4 v00 = *(const float4*)(ybase[i][0] + k0 + sa_k);
                const float4 v01 = *(const float4*)(ybase[i][1] + k0 + sa_k);
                const float4 v10 = *(const float4*)(ybase[i][2] + k0 + sa_k);
                const float4 v11 = *(const float4*)(ybase[i][3] + k0 + sa_k);
                const float wh = uwh[i], ww = uww[i];
                av[i].x = (v00.x * (1.f - wh) + v10.x * wh) * (1.f - ww) +
                          (v01.x * (1.f - wh) + v11.x * wh) * ww;
                av[i].y = (v00.y * (1.f - wh) + v10.y * wh) * (1.f - ww) +
                          (v01.y * (1.f - wh) + v11.y * wh) * ww;
                av[i].z = (v00.z * (1.f - wh) + v10.z * wh) * (1.f - ww) +
                          (v01.z * (1.f - wh) + v11.z * wh) * ww;
                av[i].w = (v00.w * (1.f - wh) + v10.w * wh) * (1.f - ww) +
                          (v01.w * (1.f - wh) + v11.w * wh) * ww;
            } else {
                av[i] = *(const float4*)(A + (size_t)(m0 + sa_m + i * 64) * K + k0 + sa_k);
            }
        }
        float4 bv[BIT];
#pragma unroll
        for (int i = 0; i < BIT; ++i) {
            const int f  = tid + i * 256;
            const int kl = f / (BN / 4);
            const int n4 = f - kl * (BN / 4);
            bv[i] = *(const float4*)(Wt + (size_t)(k0 + kl) * N + n0 + n4 * 4);
        }
        __syncthreads();   // previous iteration's LDS reads done
#pragma unroll
        for (int i = 0; i < AIT; ++i) {
            As[sa_k + 0][sa_m + i * 64] = av[i].x;
            As[sa_k + 1][sa_m + i * 64] = av[i].y;
            As[sa_k + 2][sa_m + i * 64] = av[i].z;
            As[sa_k + 3][sa_m + i * 64] = av[i].w;
        }
#pragma unroll
        for (int i = 0; i < BIT; ++i) {
            const int f  = tid + i * 256;
            const int kl = f / (BN / 4);
            const int n4 = f - kl * (BN / 4);
            *(float4*)&Bs[kl][n4 * 4] = bv[i];
        }
        __syncthreads();
#pragma unroll
        for (int kk = 0; kk < BK; ++kk) {
            float a[RT];
#pragma unroll
            for (int q = 0; q < RT / 4; ++q) {
                float4 t = *(const float4*)&As[kk][tm * RT + q * 4];
                a[q * 4 + 0] = t.x; a[q * 4 + 1] = t.y;
                a[q * 4 + 2] = t.z; a[q * 4 + 3] = t.w;
            }
            float b[NT];
#pragma unroll
            for (int q = 0; q < NT / 4; ++q) {
                float4 t = *(const float4*)&Bs[kk][tn * NT + q * 4];
                b[q * 4 + 0] = t.x; b[q * 4 + 1] = t.y;
                b[q * 4 + 2] = t.z; b[q * 4 + 3] = t.w;
            }
#pragma unroll
            for (int r = 0; r < RT; ++r)
#pragma unroll
                for (int c = 0; c < NT; ++c)
                    acc[r][c] = fmaf(a[r], b[c], acc[r][c]);
        }
    }

    // epilogue: bias, qscale, store
#pragma unroll
    for (int c = 0; c < NT; ++c) {
        const int n = n0 + tn * NT + c;
        const float bz = bias[n];
        const float sc = (n < qcols) ? qscale : 1.f;
#pragma unroll
        for (int r = 0; r < RT; ++r) acc[r][c] = (acc[r][c] + bz) * sc;
    }
    if (TRANS) {
#pragma unroll
        for (int c = 0; c < NT; ++c) {
            const int n = n0 + tn * NT + c;
            float* op = out + (size_t)n * M + m0 + tm * RT;
#pragma unroll
            for (int q = 0; q < RT / 4; ++q)
                *(float4*)(op + q * 4) = make_float4(acc[q * 4][c], acc[q * 4 + 1][c],
                                                     acc[q * 4 + 2][c], acc[q * 4 + 3][c]);
        }
    } else {
#pragma unroll
        for (int r = 0; r < RT; ++r) {
            float* op = out + (size_t)(m0 + tm * RT + r) * N + n0 + tn * NT;
#pragma unroll
            for (int q = 0; q < NT / 4; ++q)
                *(float4*)(op + q * 4) = make_float4(acc[r][q * 4], acc[r][q * 4 + 1],
                                                     acc[r][q * 4 + 2], acc[r][q * 4 + 3]);
        }
    }
}

template <int VPL>
__device__ inline void loadv(const float* __restrict__ p, float* d) {
    if constexpr (VPL == 2) {
        float2 t = *(const float2*)p;
        d[0] = t.x; d[1] = t.y;
    } else if constexpr (VPL == 4) {
        float4 t = *(const float4*)p;
        d[0] = t.x; d[1] = t.y; d[2] = t.z; d[3] = t.w;
    } else {
        float4 t0 = *(const float4*)p;
        float4 t1 = *(const float4*)(p + 4);
        d[0] = t0.x; d[1] = t0.y; d[2] = t0.z; d[3] = t0.w;
        d[4] = t1.x; d[5] = t1.y; d[6] = t1.z; d[7] = t1.w;
    }
}

// Neighborhood attention v4: 4 pixels per wave (16-lane channel groups),
// neighbor loads batched 5-at-a-time (one kernel row per batch) so 10
// global_load_dwordx4 are in flight per batch instead of serialized.
template <int C>
__global__ __launch_bounds__(256) void na2d_attn_v4(
        const float* __restrict__ qkv, const float* __restrict__ rpb,
        float* __restrict__ out, int H, int W) {
    constexpr int VPL = C / 16;  // 2 / 4 / 8
    const int lane = threadIdx.x & 63;
    const int g    = lane >> 4;
    const int li   = lane & 15;
    const int wave = threadIdx.x >> 6;
    const int pix  = (blockIdx.x * 4 + wave) * 4 + g;
    const int h = pix / W;
    const int w = pix - h * W;
    const int h0 = min(max(h - 2, 0), H - 5);
    const int w0 = min(max(w - 2, 0), W - 5);
    const int cb = li * VPL;
    const int bih = h0 - h + 4;
    const int biw = w0 - w + 4;

    float qf[VPL];
    loadv<VPL>(qkv + (size_t)pix * (3 * C) + cb, qf);

    float p[25];
#pragma unroll
    for (int jr = 0; jr < 5; ++jr) {
        const float* rowk = qkv + (size_t)((h0 + jr) * W + w0) * (3 * C) + C + cb;
        float kf[5][VPL];
#pragma unroll
        for (int jc = 0; jc < 5; ++jc) loadv<VPL>(rowk + jc * 3 * C, kf[jc]);
#pragma unroll
        for (int jc = 0; jc < 5; ++jc) {
            float s = qf[0] * kf[jc][0];
#pragma unroll
            for (int v = 1; v < VPL; ++v) s = fmaf(qf[v], kf[jc][v], s);
            p[jr * 5 + jc] = s;
        }
    }

#pragma unroll
    for (int jr = 0; jr < 5; ++jr)
#pragma unroll
        for (int jc = 0; jc < 5; ++jc) {
            const int j = jr * 5 + jc;
            float v = p[j];
            v += __shfl_xor(v, 1);
            v += __shfl_xor(v, 2);
            v += __shfl_xor(v, 4);
            v += __shfl_xor(v, 8);
            p[j] = v + rpb[(bih + jr) * 9 + (biw + jc)];
        }

    float mx = p[0];
#pragma unroll
    for (int j = 1; j < 25; ++j) mx = fmaxf(mx, p[j]);
    float sum = 0.f;
#pragma unroll
    for (int j = 0; j < 25; ++j) {
        p[j] = expf(p[j] - mx);
        sum += p[j];
    }
    const float inv = 1.f / sum;

    float a[VPL];
#pragma unroll
    for (int v = 0; v < VPL; ++v) a[v] = 0.f;
#pragma unroll
    for (int jr = 0; jr < 5; ++jr) {
        const float* rowv = qkv + (size_t)((h0 + jr) * W + w0) * (3 * C) + 2 * C + cb;
        float vf[5][VPL];
#pragma unroll
        for (int jc = 0; jc < 5; ++jc) loadv<VPL>(rowv + jc * 3 * C, vf[jc]);
#pragma unroll
        for (int jc = 0; jc < 5; ++jc)
#pragma unroll
            for (int v = 0; v < VPL; ++v) a[v] = fmaf(p[jr * 5 + jc], vf[jc][v], a[v]);
    }

    float* op = out + (size_t)pix * C + cb;
    if constexpr (VPL == 2) {
        *(float2*)op = make_float2(a[0] * inv, a[1] * inv);
    } else if constexpr (VPL == 4) {
        *(float4*)op = make_float4(a[0] * inv, a[1] * inv, a[2] * inv, a[3] * inv);
    } else {
        *(float4*)op       = make_float4(a[0] * inv, a[1] * inv, a[2] * inv, a[3] * inv);
        *(float4*)(op + 4) = make_float4(a[4] * inv, a[5] * inv, a[6] * inv, a[7] * inv);
    }
}

extern "C" void kernel_launch(void* const* d_in, const int* in_sizes, int n_in,
                              void* d_out, int out_size, void* d_ws, size_t ws_size,
                              hipStream_t stream) {
    const float* attn    = (const float*)d_in[0];
    const float* w_qkv1  = (const float*)d_in[1];
    const float* b_qkv1  = (const float*)d_in[2];
    const float* w_proj1 = (const float*)d_in[3];
    const float* b_proj1 = (const float*)d_in[4];
    const float* rpb1    = (const float*)d_in[5];
    const float* w_qkv2  = (const float*)d_in[6];
    const float* b_qkv2  = (const float*)d_in[7];
    const float* w_proj2 = (const float*)d_in[8];
    const float* b_proj2 = (const float*)d_in[9];
    const float* rpb2    = (const float*)d_in[10];
    const float* w_qkv3  = (const float*)d_in[11];
    const float* b_qkv3  = (const float*)d_in[12];
    const float* w_proj3 = (const float*)d_in[13];
    const float* b_proj3 = (const float*)d_in[14];
    const float* rpb3    = (const float*)d_in[15];
    const float* w_up1   = (const float*)d_in[16];
    const float* b_up1   = (const float*)d_in[17];
    const float* w_up2   = (const float*)d_in[18];
    const float* b_up2   = (const float*)d_in[19];
    float* out = (float*)d_out;

    float* ws   = (float*)d_ws;
    float* bufA = ws;                        // x (HWC)   (max 18432*128)
    float* bufB = bufA + 2359296;            // qkv       (max 18432*384)
    float* bufC = bufB + 7077888;            // attn out  (max 18432*128)
    float* bufD = bufC + 2359296;            // y = proj out (max 4608*64)

    // ---- Stage 1: C=32, 24x48, M=1152 ----
    {
        const int H = 24, W = 48, C = 32, M = H * W;
        mm_bias<16, 1><<<M / 16, 3 * C, 16 * C * 4, stream>>>(
            attn, w_qkv1, b_qkv1, bufB, M, C, 3 * C, C, 1.f / sqrtf((float)C));
        na2d_attn_v4<32><<<M / 16, 256, 0, stream>>>(bufB, rpb1, bufC, H, W);
        mm_bias<16, 0><<<M / 16, C, 16 * C * 4, stream>>>(
            bufC, w_proj1, b_proj1, bufD, M, C, C, 0, 1.f);
        // fused up2x(24x48->48x96) + matmul (K=32 -> N=64)
        gemm_rt<64, 64, 4, 0, 1><<<dim3(4 * M / 64, 1), 256, 0, stream>>>(
            bufD, w_up1, b_up1, bufA, 4 * M, C, 64, 0, 1.f, H, W);
    }
    // ---- Stage 2: C=64, 48x96, M=4608 ----
    {
        const int H = 48, W = 96, C = 64, M = H * W;
        gemm_rt<64, 64, 4, 0, 0><<<dim3(M / 64, 3), 256, 0, stream>>>(
            bufA, w_qkv2, b_qkv2, bufB, M, C, 3 * C, C, 1.f / sqrtf((float)C), 0, 0);
        na2d_attn_v4<64><<<M / 16, 256, 0, stream>>>(bufB, rpb2, bufC, H, W);
        gemm_rt<64, 64, 4, 0, 0><<<dim3(M / 64, 1), 256, 0, stream>>>(
            bufC, w_proj2, b_proj2, bufD, M, C, C, 0, 1.f, 0, 0);
        // fused up2x(48x96->96x192) + matmul (K=64 -> N=128)
        gemm_rt<128, 128, 8, 0, 1><<<dim3(4 * M / 128, 1), 256, 0, stream>>>(
            bufD, w_up2, b_up2, bufA, 4 * M, C, 128, 0, 1.f, H, W);
    }
    // ---- Stage 3: C=128, 96x192, M=18432 ----
    {
        const int H = 96, W = 192, C = 128, M = H * W;
        gemm_rt<128, 128, 8, 0, 0><<<dim3(M / 128, 3), 256, 0, stream>>>(
            bufA, w_qkv3, b_qkv3, bufB, M, C, 3 * C, C, 1.f / sqrtf((float)C), 0, 0);
        na2d_attn_v4<128><<<M / 16, 256, 0, stream>>>(bufB, rpb3, bufC, H, W);
        gemm_rt<128, 128, 8, 1, 0><<<dim3(M / 128, 1), 256, 0, stream>>>(
            bufC, w_proj3, b_proj3, out, M, C, C, 0, 1.f, 0, 0);  // -> CHW
    }
}

// Round 12
// 108.065 us; speedup vs baseline: 4.1321x; 1.3983x over previous
//
#include <hip/hip_runtime.h>
#include <math.h>

// ---------------------------------------------------------------------------
// Refine_Attn: 3-level neighborhood-attention pyramid, fp32.
// Stage 1: C=32,  24x48 | Stage 2: C=64, 48x96 | Stage 3: C=128, 96x192
// k=5 neighborhood, rpb bias (9x9), softmax over 25, proj, bilinear up2x.
//
// Key identity: up2x(y) @ Wup + bup feeds ONLY the next qkv matmul, so
//   qkv = up2x(y) @ (Wup@Wqkv) + (bup@Wqkv + bqkv)   (weights composed once).
// Launch plan (7 dispatches):
//   compose2 -> qkv1(mm,CHW gather) -> na2d_proj1 -> qkvup2(UP-GEMM)
//            -> na2d_proj2 -> qkvup3(UP-GEMM) -> na2d_proj3 (CHW out)
// ---------------------------------------------------------------------------

// Weight composition: Wc = Wup @ Wqkv, bc = bup @ Wqkv + bqkv (both stages).
__global__ void compose2(const float* __restrict__ Wu1, const float* __restrict__ bu1,
                         const float* __restrict__ Wq2, const float* __restrict__ bq2,
                         const float* __restrict__ Wu2, const float* __restrict__ bu2,
                         const float* __restrict__ Wq3, const float* __restrict__ bq3,
                         float* __restrict__ Wc1, float* __restrict__ bc1,
                         float* __restrict__ Wc2, float* __restrict__ bc2) {
    int idx = blockIdx.x * blockDim.x + threadIdx.x;
    const int R1 = 33 * 192;           // 32 weight rows + 1 bias row
    if (idx < R1) {
        const int r = idx / 192;
        const int n = idx - r * 192;
        const float* wp = Wq2 + n;
        const float* a  = (r < 32) ? Wu1 + r * 64 : bu1;
        float s = 0.f;
        for (int k = 0; k < 64; ++k) s = fmaf(a[k], wp[(size_t)k * 192], s);
        if (r < 32) Wc1[r * 192 + n] = s;
        else        bc1[n] = s + bq2[n];
    } else {
        idx -= R1;
        if (idx >= 65 * 384) return;
        const int r = idx / 384;
        const int n = idx - r * 384;
        const float* wp = Wq3 + n;
        const float* a  = (r < 64) ? Wu2 + r * 128 : bu2;
        float s = 0.f;
        for (int k = 0; k < 128; ++k) s = fmaf(a[k], wp[(size_t)k * 384], s);
        if (r < 64) Wc2[r * 384 + n] = s;
        else        bc2[n] = s + bq3[n];
    }
}

// Small-matrix broadcast matmul (stage-1 qkv only).
// CHW: A is (K, HW); gather A[m][k] = A[k*HW+m] during staging.
template <int MT, int CHW>
__global__ void mm_bias(const float* __restrict__ A, const float* __restrict__ Wt,
                        const float* __restrict__ bias, float* __restrict__ out,
                        int M, int K, int N, int qcols, float qscale) {
    extern __shared__ float As[];  // MT*K floats
    const int m0 = blockIdx.x * MT;
    const int n  = threadIdx.x;
    if (CHW) {
        for (int idx = n; idx < MT * K; idx += blockDim.x) {
            const int r = idx / K;
            const int k = idx - r * K;
            As[idx] = A[(size_t)k * M + m0 + r];
        }
    } else {
        const float4* src = (const float4*)(A + (size_t)m0 * K);
        float4* dst = (float4*)As;
        for (int idx = n; idx < MT * K / 4; idx += blockDim.x) dst[idx] = src[idx];
    }
    __syncthreads();

    float acc[MT];
#pragma unroll
    for (int r = 0; r < MT; ++r) acc[r] = bias[n];
    for (int k = 0; k < K; k += 4) {
        const float* wp = Wt + (size_t)k * N + n;
        const float w0 = wp[0];
        const float w1 = wp[N];
        const float w2 = wp[2 * N];
        const float w3 = wp[3 * N];
#pragma unroll
        for (int r = 0; r < MT; ++r) {
            float4 a4 = *(const float4*)&As[r * K + k];
            acc[r] = fmaf(a4.x, w0, acc[r]);
            acc[r] = fmaf(a4.y, w1, acc[r]);
            acc[r] = fmaf(a4.z, w2, acc[r]);
            acc[r] = fmaf(a4.w, w3, acc[r]);
        }
    }
    if (n < qcols) {
#pragma unroll
        for (int r = 0; r < MT; ++r) acc[r] *= qscale;
    }
#pragma unroll
    for (int r = 0; r < MT; ++r) out[(size_t)(m0 + r) * N + n] = acc[r];
}

// Register-tiled GEMM: out = A(M,K) @ Wt(K,N) + bias; first qcols cols scaled
// by qscale after bias. Block tile BM x BN, BK=16, 256 thr, thread tile
// RT x NT (RT=BM/16, BN=16*NT). UP: A rows are bilinear 2x-upsampled y (Hs,Ws,K).
template <int BM, int BN, int NT, int TRANS, int UP>
__global__ __launch_bounds__(256) void gemm_rt(
        const float* __restrict__ A, const float* __restrict__ Wt,
        const float* __restrict__ bias, float* __restrict__ out,
        int M, int K, int N, int qcols, float qscale, int Hs, int Ws) {
    constexpr int BK = 16;
    constexpr int RT = BM / 16;
    constexpr int AIT = (BM * BK) / (4 * 256);
    constexpr int BIT = (BK * BN) / (4 * 256);
    __shared__ float As[BK][BM + 4];
    __shared__ float Bs[BK][BN + 4];
    const int tid = threadIdx.x;
    const int tn = tid >> 4;
    const int tm = tid & 15;
    const int m0 = blockIdx.x * BM;
    const int n0 = blockIdx.y * BN;

    const int sa_m = tid >> 2;
    const int sa_k = (tid & 3) << 2;

    const float* ybase[AIT][4];
    float uwh[AIT], uww[AIT];
    if (UP) {
        const int Wd = 2 * Ws, Hd = 2 * Hs;
#pragma unroll
        for (int i = 0; i < AIT; ++i) {
            const int row = m0 + sa_m + i * 64;
            const int h2 = row / Wd;
            const int w2 = row - h2 * Wd;
            const float ph = (float)h2 * (float)(Hs - 1) / (float)(Hd - 1);
            const int h0i = (int)ph;
            const int h1i = min(h0i + 1, Hs - 1);
            uwh[i] = ph - (float)h0i;
            const float pw = (float)w2 * (float)(Ws - 1) / (float)(Wd - 1);
            const int w0i = (int)pw;
            const int w1i = min(w0i + 1, Ws - 1);
            uww[i] = pw - (float)w0i;
            ybase[i][0] = A + ((size_t)h0i * Ws + w0i) * K;
            ybase[i][1] = A + ((size_t)h0i * Ws + w1i) * K;
            ybase[i][2] = A + ((size_t)h1i * Ws + w0i) * K;
            ybase[i][3] = A + ((size_t)h1i * Ws + w1i) * K;
        }
    }

    float acc[RT][NT];
#pragma unroll
    for (int r = 0; r < RT; ++r)
#pragma unroll
        for (int c = 0; c < NT; ++c) acc[r][c] = 0.f;

    for (int k0 = 0; k0 < K; k0 += BK) {
        float4 av[AIT];
#pragma unroll
        for (int i = 0; i < AIT; ++i) {
            if (UP) {
                const float4 v00 = *(const float4*)(ybase[i][0] + k0 + sa_k);
                const float4 v01 = *(const float4*)(ybase[i][1] + k0 + sa_k);
                const float4 v10 = *(const float4*)(ybase[i][2] + k0 + sa_k);
                const float4 v11 = *(const float4*)(ybase[i][3] + k0 + sa_k);
                const float wh = uwh[i], ww = uww[i];
                av[i].x = (v00.x * (1.f - wh) + v10.x * wh) * (1.f - ww) +
                          (v01.x * (1.f - wh) + v11.x * wh) * ww;
                av[i].y = (v00.y * (1.f - wh) + v10.y * wh) * (1.f - ww) +
                          (v01.y * (1.f - wh) + v11.y * wh) * ww;
                av[i].z = (v00.z * (1.f - wh) + v10.z * wh) * (1.f - ww) +
                          (v01.z * (1.f - wh) + v11.z * wh) * ww;
                av[i].w = (v00.w * (1.f - wh) + v10.w * wh) * (1.f - ww) +
                          (v01.w * (1.f - wh) + v11.w * wh) * ww;
            } else {
                av[i] = *(const float4*)(A + (size_t)(m0 + sa_m + i * 64) * K + k0 + sa_k);
            }
        }
        float4 bv[BIT];
#pragma unroll
        for (int i = 0; i < BIT; ++i) {
            const int f  = tid + i * 256;
            const int kl = f / (BN / 4);
            const int n4 = f - kl * (BN / 4);
            bv[i] = *(const float4*)(Wt + (size_t)(k0 + kl) * N + n0 + n4 * 4);
        }
        __syncthreads();
#pragma unroll
        for (int i = 0; i < AIT; ++i) {
            As[sa_k + 0][sa_m + i * 64] = av[i].x;
            As[sa_k + 1][sa_m + i * 64] = av[i].y;
            As[sa_k + 2][sa_m + i * 64] = av[i].z;
            As[sa_k + 3][sa_m + i * 64] = av[i].w;
        }
#pragma unroll
        for (int i = 0; i < BIT; ++i) {
            const int f  = tid + i * 256;
            const int kl = f / (BN / 4);
            const int n4 = f - kl * (BN / 4);
            *(float4*)&Bs[kl][n4 * 4] = bv[i];
        }
        __syncthreads();
#pragma unroll
        for (int kk = 0; kk < BK; ++kk) {
            float a[RT];
#pragma unroll
            for (int q = 0; q < RT / 4; ++q) {
                float4 t = *(const float4*)&As[kk][tm * RT + q * 4];
                a[q * 4 + 0] = t.x; a[q * 4 + 1] = t.y;
                a[q * 4 + 2] = t.z; a[q * 4 + 3] = t.w;
            }
            float b[NT];
#pragma unroll
            for (int q = 0; q < NT / 4; ++q) {
                float4 t = *(const float4*)&Bs[kk][tn * NT + q * 4];
                b[q * 4 + 0] = t.x; b[q * 4 + 1] = t.y;
                b[q * 4 + 2] = t.z; b[q * 4 + 3] = t.w;
            }
#pragma unroll
            for (int r = 0; r < RT; ++r)
#pragma unroll
                for (int c = 0; c < NT; ++c)
                    acc[r][c] = fmaf(a[r], b[c], acc[r][c]);
        }
    }

#pragma unroll
    for (int c = 0; c < NT; ++c) {
        const int n = n0 + tn * NT + c;
        const float bz = bias[n];
        const float sc = (n < qcols) ? qscale : 1.f;
#pragma unroll
        for (int r = 0; r < RT; ++r) acc[r][c] = (acc[r][c] + bz) * sc;
    }
    if (TRANS) {
#pragma unroll
        for (int c = 0; c < NT; ++c) {
            const int n = n0 + tn * NT + c;
            float* op = out + (size_t)n * M + m0 + tm * RT;
#pragma unroll
            for (int q = 0; q < RT / 4; ++q)
                *(float4*)(op + q * 4) = make_float4(acc[q * 4][c], acc[q * 4 + 1][c],
                                                     acc[q * 4 + 2][c], acc[q * 4 + 3][c]);
        }
    } else {
#pragma unroll
        for (int r = 0; r < RT; ++r) {
            float* op = out + (size_t)(m0 + tm * RT + r) * N + n0 + tn * NT;
#pragma unroll
            for (int q = 0; q < NT / 4; ++q)
                *(float4*)(op + q * 4) = make_float4(acc[r][q * 4], acc[r][q * 4 + 1],
                                                     acc[r][q * 4 + 2], acc[r][q * 4 + 3]);
        }
    }
}

template <int VPL>
__device__ inline void loadv(const float* __restrict__ p, float* d) {
    if constexpr (VPL == 2) {
        float2 t = *(const float2*)p;
        d[0] = t.x; d[1] = t.y;
    } else if constexpr (VPL == 4) {
        float4 t = *(const float4*)p;
        d[0] = t.x; d[1] = t.y; d[2] = t.z; d[3] = t.w;
    } else {
        float4 t0 = *(const float4*)p;
        float4 t1 = *(const float4*)(p + 4);
        d[0] = t0.x; d[1] = t0.y; d[2] = t0.z; d[3] = t0.w;
        d[4] = t1.x; d[5] = t1.y; d[6] = t1.z; d[7] = t1.w;
    }
}

// Fused neighborhood attention + proj. 256 threads = 4 waves; each wave 4
// pixels (v4 structure: 16-lane channel groups, row-batched loads). The 16
// attention rows stay in LDS; then a 16xC @ CxC proj GEMM (W staged via LDS).
// TRANS: out[n][m] (CHW, stage 3).
template <int C, int TRANS>
__global__ __launch_bounds__(256) void na2d_proj(
        const float* __restrict__ qkv, const float* __restrict__ rpb,
        const float* __restrict__ Wp, const float* __restrict__ bp,
        float* __restrict__ out, int H, int W, int M) {
    constexpr int VPL = C / 16;   // channels per lane (phase A)
    constexpr int NT  = C / 16;   // cols per thread (phase B)
    __shared__ float att_s[16][C + 4];  // +4: 16B-aligned rows, bank-spread
    __shared__ float Bs[16][C];
    const int tid  = threadIdx.x;
    const int lane = tid & 63;
    const int g    = lane >> 4;
    const int li   = lane & 15;
    const int wave = tid >> 6;
    const int lp   = wave * 4 + g;           // local pixel 0..15
    const int pix  = blockIdx.x * 16 + lp;
    const int h = pix / W;
    const int w = pix - h * W;
    const int h0 = min(max(h - 2, 0), H - 5);
    const int w0 = min(max(w - 2, 0), W - 5);
    const int cb = li * VPL;
    const int bih = h0 - h + 4;
    const int biw = w0 - w + 4;

    // ---- phase A: attention (identical math to na2d_attn_v4) ----
    float qf[VPL];
    loadv<VPL>(qkv + (size_t)pix * (3 * C) + cb, qf);

    float p[25];
#pragma unroll
    for (int jr = 0; jr < 5; ++jr) {
        const float* rowk = qkv + (size_t)((h0 + jr) * W + w0) * (3 * C) + C + cb;
        float kf[5][VPL];
#pragma unroll
        for (int jc = 0; jc < 5; ++jc) loadv<VPL>(rowk + jc * 3 * C, kf[jc]);
#pragma unroll
        for (int jc = 0; jc < 5; ++jc) {
            float s = qf[0] * kf[jc][0];
#pragma unroll
            for (int v = 1; v < VPL; ++v) s = fmaf(qf[v], kf[jc][v], s);
            p[jr * 5 + jc] = s;
        }
    }
#pragma unroll
    for (int jr = 0; jr < 5; ++jr)
#pragma unroll
        for (int jc = 0; jc < 5; ++jc) {
            const int j = jr * 5 + jc;
            float v = p[j];
            v += __shfl_xor(v, 1);
            v += __shfl_xor(v, 2);
            v += __shfl_xor(v, 4);
            v += __shfl_xor(v, 8);
            p[j] = v + rpb[(bih + jr) * 9 + (biw + jc)];
        }
    float mx = p[0];
#pragma unroll
    for (int j = 1; j < 25; ++j) mx = fmaxf(mx, p[j]);
    float sum = 0.f;
#pragma unroll
    for (int j = 0; j < 25; ++j) {
        p[j] = expf(p[j] - mx);
        sum += p[j];
    }
    const float inv = 1.f / sum;

    float a[VPL];
#pragma unroll
    for (int v = 0; v < VPL; ++v) a[v] = 0.f;
#pragma unroll
    for (int jr = 0; jr < 5; ++jr) {
        const float* rowv = qkv + (size_t)((h0 + jr) * W + w0) * (3 * C) + 2 * C + cb;
        float vf[5][VPL];
#pragma unroll
        for (int jc = 0; jc < 5; ++jc) loadv<VPL>(rowv + jc * 3 * C, vf[jc]);
#pragma unroll
        for (int jc = 0; jc < 5; ++jc)
#pragma unroll
            for (int v = 0; v < VPL; ++v) a[v] = fmaf(p[jr * 5 + jc], vf[jc][v], a[v]);
    }
#pragma unroll
    for (int v = 0; v < VPL; ++v) att_s[lp][cb + v] = a[v] * inv;

    // ---- phase B: proj 16xC @ CxC + bias ----
    const int tm = tid & 15;
    const int tn = tid >> 4;
    constexpr int WPT = C / 16;          // Bs floats staged per thread
    const int skl = tid >> 4;            // k-row within tile
    const int snn = (tid & 15) * WPT;    // col offset
    float acc[NT];
#pragma unroll
    for (int c = 0; c < NT; ++c) acc[c] = bp[tn * NT + c];

    for (int k0 = 0; k0 < C; k0 += 16) {
        float tmp[WPT];
        {
            const float* src = Wp + (size_t)(k0 + skl) * C + snn;
#pragma unroll
            for (int t = 0; t < WPT; ++t) tmp[t] = src[t];
        }
        __syncthreads();   // prev iter's Bs reads done; (iter 0: att_s visible)
#pragma unroll
        for (int t = 0; t < WPT; ++t) Bs[skl][snn + t] = tmp[t];
        __syncthreads();
#pragma unroll
        for (int kk = 0; kk < 16; ++kk) {
            const float av = att_s[tm][k0 + kk];
            const float* bsp = &Bs[kk][tn * NT];
#pragma unroll
            for (int c = 0; c < NT; ++c) acc[c] = fmaf(av, bsp[c], acc[c]);
        }
    }

    const int m0 = blockIdx.x * 16;
    if (TRANS) {
#pragma unroll
        for (int c = 0; c < NT; ++c)
            out[(size_t)(tn * NT + c) * M + m0 + tm] = acc[c];
    } else {
        float* op = out + (size_t)(m0 + tm) * C + tn * NT;
#pragma unroll
        for (int c = 0; c < NT; ++c) op[c] = acc[c];
    }
}

extern "C" void kernel_launch(void* const* d_in, const int* in_sizes, int n_in,
                              void* d_out, int out_size, void* d_ws, size_t ws_size,
                              hipStream_t stream) {
    const float* attn    = (const float*)d_in[0];
    const float* w_qkv1  = (const float*)d_in[1];
    const float* b_qkv1  = (const float*)d_in[2];
    const float* w_proj1 = (const float*)d_in[3];
    const float* b_proj1 = (const float*)d_in[4];
    const float* rpb1    = (const float*)d_in[5];
    const float* w_qkv2  = (const float*)d_in[6];
    const float* b_qkv2  = (const float*)d_in[7];
    const float* w_proj2 = (const float*)d_in[8];
    const float* b_proj2 = (const float*)d_in[9];
    const float* rpb2    = (const float*)d_in[10];
    const float* w_qkv3  = (const float*)d_in[11];
    const float* b_qkv3  = (const float*)d_in[12];
    const float* w_proj3 = (const float*)d_in[13];
    const float* b_proj3 = (const float*)d_in[14];
    const float* rpb3    = (const float*)d_in[15];
    const float* w_up1   = (const float*)d_in[16];
    const float* b_up1   = (const float*)d_in[17];
    const float* w_up2   = (const float*)d_in[18];
    const float* b_up2   = (const float*)d_in[19];
    float* out = (float*)d_out;

    float* ws   = (float*)d_ws;
    float* bufB = ws + 2359296;              // qkv   (max 18432*384)
    float* bufD = bufB + 7077888;            // y     (max 4608*64)
    float* wc1  = bufD + 294912;             // 32x192 composed up1->qkv2
    float* bc1  = wc1 + 6144;                // 192
    float* wc2  = bc1 + 192;                 // 64x384 composed up2->qkv3
    float* bc2  = wc2 + 24576;               // 384

    // ---- weight composition (weights only; no data dependence) ----
    compose2<<<(33 * 192 + 65 * 384 + 255) / 256, 256, 0, stream>>>(
        w_up1, b_up1, w_qkv2, b_qkv2, w_up2, b_up2, w_qkv3, b_qkv3,
        wc1, bc1, wc2, bc2);

    // ---- Stage 1: C=32, 24x48, M=1152 ----
    {
        const int H = 24, W = 48, C = 32, M = H * W;
        mm_bias<16, 1><<<M / 16, 3 * C, 16 * C * 4, stream>>>(
            attn, w_qkv1, b_qkv1, bufB, M, C, 3 * C, C, 1.f / sqrtf((float)C));
        na2d_proj<32, 0><<<M / 16, 256, 0, stream>>>(
            bufB, rpb1, w_proj1, b_proj1, bufD, H, W, M);
    }
    // ---- Stage 2: C=64, 48x96, M=4608; qkv2 = up2x(y1) @ wc1 + bc1 ----
    {
        const int H = 48, W = 96, C = 64, M = H * W;
        gemm_rt<64, 64, 4, 0, 1><<<dim3(M / 64, 3), 256, 0, stream>>>(
            bufD, wc1, bc1, bufB, M, 32, 3 * C, C, 1.f / sqrtf((float)C), 24, 48);
        na2d_proj<64, 0><<<M / 16, 256, 0, stream>>>(
            bufB, rpb2, w_proj2, b_proj2, bufD, H, W, M);
    }
    // ---- Stage 3: C=128, 96x192, M=18432; qkv3 = up2x(y2) @ wc2 + bc2 ----
    {
        const int H = 96, W = 192, C = 128, M = H * W;
        gemm_rt<128, 128, 8, 0, 1><<<dim3(M / 128, 3), 256, 0, stream>>>(
            bufD, wc2, bc2, bufB, M, 64, 3 * C, C, 1.f / sqrtf((float)C), 48, 96);
        na2d_proj<128, 1><<<M / 16, 256, 0, stream>>>(
            bufB, rpb3, w_proj3, b_proj3, out, H, W, M);  // -> CHW
    }
}